// Round 5
// baseline (2134.707 us; speedup 1.0000x reference)
//
#include <hip/hip_runtime.h>
#include <hip/hip_cooperative_groups.h>
#include <math.h>

namespace cg = cooperative_groups;

constexpr int N = 512;
constexpr int D = 16;
constexpr int E = 12;

// ---- workspace layout (float offsets) ----
constexpr size_t OFF_A     = 0;                            // E*N*N  A -> L -> iK
constexpr size_t OFF_IK    = OFF_A    + (size_t)E*N*N;     // E*N*N  W = L^{-1}
constexpr size_t OFF_XS    = OFF_IK   + (size_t)E*N*N;     // N*D
constexpr size_t OFF_INP   = OFF_XS   + (size_t)N*D;       // N*D
constexpr size_t OFF_YN    = OFF_INP  + (size_t)N*D;       // E*N
constexpr size_t OFF_BETA  = OFF_YN   + (size_t)E*N;       // E*N
constexpr size_t OFF_KVEC  = OFF_BETA + (size_t)E*N;       // E*N
constexpr size_t OFF_LB    = OFF_KVEC + (size_t)E*N;       // E*N
constexpr size_t OFF_TIL   = OFF_LB   + (size_t)E*N;       // E*N*D
constexpr size_t OFF_X1    = OFF_TIL  + (size_t)E*N*D;     // E*N*D
constexpr size_t OFF_X1Q   = OFF_X1   + (size_t)E*N*D;     // E*E*N*D
constexpr size_t OFF_XS1   = OFF_X1Q  + (size_t)E*E*N*D;   // E*E*N
constexpr size_t OFF_XS2   = OFF_XS1  + (size_t)E*E*N;     // E*E*N
constexpr size_t OFF_Q     = OFF_XS2  + (size_t)E*E*N;     // E*E*D*D
constexpr size_t OFF_BINV  = OFF_Q    + (size_t)E*E*D*D;   // E*D*D
constexpr size_t OFF_C     = OFF_BINV + (size_t)E*D*D;     // E
constexpr size_t OFF_ISDR  = OFF_C    + E;                 // E*E
constexpr size_t OFF_SPART = OFF_ISDR + E*E;               // E*E*8
constexpr size_t OFF_TPART = OFF_SPART+ (size_t)E*E*8;     // E*8
constexpr size_t OFF_XMEAN = OFF_TPART+ (size_t)E*8;       // D
constexpr size_t OFF_XSTD  = OFF_XMEAN+ D;                 // D
constexpr size_t OFF_YMEAN = OFF_XSTD + D;                 // E
constexpr size_t OFF_YSTD  = OFF_YMEAN+ E;                 // E
constexpr size_t OFF_SSM   = OFF_YSTD + E;                 // D*D

// ---------- 1. standardization ----------
__global__ __launch_bounds__(512) void k_prep(const float* __restrict__ X, const float* __restrict__ Y,
                                              const float* __restrict__ m, const float* __restrict__ s,
                                              float* __restrict__ ws) {
    int tid = threadIdx.x;
    int lane = tid & 63, wave = tid >> 6;   // 8 waves
    __shared__ float meanX[D], stdX[D], meanY[E], stdY[E], mmsh[D];

    for (int col = wave; col < D + E; col += 8) {
        float s1 = 0.f, s2 = 0.f;
        if (col < D) {
            #pragma unroll
            for (int i = 0; i < 8; ++i) { float v = X[(i*64 + lane)*D + col]; s1 += v; s2 += v*v; }
        } else {
            int e = col - D;
            #pragma unroll
            for (int i = 0; i < 8; ++i) { float v = Y[(i*64 + lane)*E + e]; s1 += v; s2 += v*v; }
        }
        #pragma unroll
        for (int off = 32; off > 0; off >>= 1) { s1 += __shfl_xor(s1, off); s2 += __shfl_xor(s2, off); }
        if (lane == 0) {
            float mean = s1 * (1.0f/N);
            float var  = (s2 - (float)N*mean*mean) * (1.0f/(N-1));
            float sd   = sqrtf(var);
            if (col < D) { meanX[col] = mean; stdX[col] = sd; }
            else         { meanY[col-D] = mean; stdY[col-D] = sd; }
        }
    }
    __syncthreads();
    if (tid < D) {
        mmsh[tid] = (m[tid] - meanX[tid]) / stdX[tid];
        ws[OFF_XMEAN + tid] = meanX[tid];
        ws[OFF_XSTD  + tid] = stdX[tid];
    }
    if (tid < E) { ws[OFF_YMEAN + tid] = meanY[tid]; ws[OFF_YSTD + tid] = stdY[tid]; }
    __syncthreads();
    int n = tid;
    #pragma unroll
    for (int d = 0; d < D; ++d) {
        float xs = (X[n*D + d] - meanX[d]) / stdX[d];
        ws[OFF_XS  + n*D + d] = xs;
        ws[OFF_INP + n*D + d] = xs - mmsh[d];
    }
    #pragma unroll
    for (int e = 0; e < E; ++e)
        ws[OFF_YN + e*N + n] = (Y[n*E + e] - meanY[e]) / stdY[e];
    if (tid < D*D) {
        int i = tid / D, j = tid % D;
        ws[OFF_SSM + tid] = s[tid] / (stdX[i] * stdX[j]);
    }
}

// ---------- 2. A = K + noise I (64x64 tiles) ----------
__global__ __launch_bounds__(256) void k_buildA(float* __restrict__ ws, const float* __restrict__ ls,
                                                const float* __restrict__ os, const float* __restrict__ noise) {
    int bid = blockIdx.x;            // E * 8 * 8
    int e  = bid >> 6;
    int t  = bid & 63;
    int bn = t >> 3, bm = t & 7;
    int tid = threadIdx.x;
    __shared__ float xn[64][17], xm[64][17];
    __shared__ float il2[16];
    for (int idx = tid; idx < 1024; idx += 256) {
        int r = idx >> 4, d0 = idx & 15;
        xn[r][d0] = ws[OFF_XS + (size_t)(bn*64 + r)*D + d0];
        xm[r][d0] = ws[OFF_XS + (size_t)(bm*64 + r)*D + d0];
    }
    if (tid < 16) { float l = ls[e*D + tid]; il2[tid] = 1.0f/(l*l); }
    __syncthreads();
    int tx = tid & 15, ty = tid >> 4;
    float osv = os[e], nsv = noise[e];
    float acc[4][4] = {};
    #pragma unroll
    for (int d = 0; d < 16; ++d) {
        float il = il2[d];
        float an[4], am[4];
        #pragma unroll
        for (int q = 0; q < 4; ++q) { an[q] = xn[ty + q*16][d]; am[q] = xm[tx + q*16][d]; }
        #pragma unroll
        for (int q = 0; q < 4; ++q)
            #pragma unroll
            for (int w = 0; w < 4; ++w) { float df = an[q] - am[w]; acc[q][w] = fmaf(df*df, il, acc[q][w]); }
    }
    float* A = ws + OFF_A + (size_t)e*N*N;
    #pragma unroll
    for (int q = 0; q < 4; ++q)
        #pragma unroll
        for (int w = 0; w < 4; ++w) {
            int nr = bn*64 + ty + q*16, mc = bm*64 + tx + w*16;
            float v = osv * __expf(-0.5f * acc[q][w]);
            if (nr == mc) v += nsv;
            A[(size_t)nr*N + mc] = v;
        }
}

// =================== cooperative factorization kernel phases ===================
// smem: 12480 floats (49.9 KB), carved per phase.

__device__ void diag_body(float* __restrict__ ws, float* __restrict__ smem, int e, int k0, int tid) {
    float (*Lsh)[68] = (float(*)[68])smem;          // 64*68 = 4352
    float* colbuf = smem + 4352;                    // 64
    float* invdsh = smem + 4416;                    // 64
    const float* A = ws + OFF_A + (size_t)e*N*N;
    float* W = ws + OFF_IK + (size_t)e*N*N;
    int lane = tid;
    bool act = tid < 64;
    float a[64];
    if (act) {
        #pragma unroll
        for (int c = 0; c < 64; ++c) a[c] = A[(size_t)(k0 + c)*N + k0 + lane];  // symmetric: coalesced
    }
    #pragma unroll
    for (int k = 0; k < 64; ++k) {
        if (act && lane == k) {
            float dv = sqrtf(a[k]);
            a[k] = dv;
            colbuf[k] = dv;
            invdsh[k] = 1.0f / dv;
        }
        __syncthreads();
        if (act && lane > k) {
            a[k] *= invdsh[k];
            colbuf[lane] = a[k];
        }
        __syncthreads();
        if (act) {
            float lrk = a[k];
            #pragma unroll
            for (int c = k + 1; c < 64; ++c)
                a[c] = fmaf(-lrk, colbuf[c], a[c]);   // upper-tri lanes produce dead garbage only
        }
        __syncthreads();
    }
    if (act) {
        #pragma unroll
        for (int c4 = 0; c4 < 16; ++c4) {
            float4 v; v.x = a[c4*4]; v.y = a[c4*4+1]; v.z = a[c4*4+2]; v.w = a[c4*4+3];
            *(float4*)&Lsh[lane][c4*4] = v;
        }
    }
    __syncthreads();
    if (act) {
        float x[64];
        int c = lane;
        #pragma unroll
        for (int r = 0; r < 64; ++r) {
            float acc0 = (r == c) ? 1.0f : 0.0f, acc1 = 0.f, acc2 = 0.f, acc3 = 0.f;
            #pragma unroll
            for (int k4 = 0; k4 < (r >> 2); ++k4) {
                float4 L4 = *(const float4*)&Lsh[r][k4*4];
                acc0 = fmaf(-L4.x, x[k4*4+0], acc0);
                acc1 = fmaf(-L4.y, x[k4*4+1], acc1);
                acc2 = fmaf(-L4.z, x[k4*4+2], acc2);
                acc3 = fmaf(-L4.w, x[k4*4+3], acc3);
            }
            #pragma unroll
            for (int k = r & ~3; k < r; ++k)
                acc0 = fmaf(-Lsh[r][k], x[k], acc0);
            x[r] = ((acc0 + acc1) + (acc2 + acc3)) * invdsh[r];
        }
        #pragma unroll
        for (int r = 0; r < 64; ++r)
            W[(size_t)(k0 + r)*N + k0 + c] = x[r];
    }
    __syncthreads();
}

__device__ void panel_body(float* __restrict__ ws, float* __restrict__ smem, int e, int bi, int k0, int tid) {
    float (*Ps)[65]  = (float(*)[65])smem;
    float (*Wsh)[65] = (float(*)[65])(smem + 4160);
    float* A = ws + OFF_A + (size_t)e*N*N;
    const float* W = ws + OFF_IK + (size_t)e*N*N;
    int r0 = k0 + 64 + bi*64;
    __syncthreads();
    for (int idx = tid; idx < 4096; idx += 256) {
        int r = idx >> 6, c2 = idx & 63;
        Ps[r][c2]  = A[(size_t)(r0 + r)*N + k0 + c2];
        Wsh[r][c2] = W[(size_t)(k0 + r)*N + k0 + c2];
    }
    __syncthreads();
    int tx = tid & 15, ty = tid >> 4;
    float acc[4][4] = {};
    #pragma unroll 8
    for (int j = 0; j < 64; ++j) {
        float pr[4], wr[4];
        #pragma unroll
        for (int q = 0; q < 4; ++q) { pr[q] = Ps[ty*4+q][j]; wr[q] = Wsh[tx*4+q][j]; }
        #pragma unroll
        for (int q = 0; q < 4; ++q)
            #pragma unroll
            for (int w = 0; w < 4; ++w) acc[q][w] = fmaf(pr[q], wr[w], acc[q][w]);
    }
    __syncthreads();
    #pragma unroll
    for (int q = 0; q < 4; ++q)
        #pragma unroll
        for (int w = 0; w < 4; ++w)
            A[(size_t)(r0 + ty*4 + q)*N + k0 + tx*4 + w] = acc[q][w];
}

__device__ void trail_body(float* __restrict__ ws, float* __restrict__ smem, int task, int k0, int tid) {
    int t0 = k0 + 64;
    int nb = (N - t0) >> 6;
    int ntiles = (nb*(nb+1)) >> 1;
    int e = task / ntiles;
    int t = task % ntiles;
    int bj = 0; while (t >= nb - bj) { t -= nb - bj; ++bj; }
    int bi = bj + t;
    float* A = ws + OFF_A + (size_t)e*N*N;
    const float* Pr = A + (size_t)(t0 + bi*64)*N + k0;
    const float* Pc = A + (size_t)(t0 + bj*64)*N + k0;
    float (*Sr)[65] = (float(*)[65])smem;
    float (*Sc)[65] = (float(*)[65])(smem + 4160);
    __syncthreads();
    for (int idx = tid; idx < 4096; idx += 256) {
        int r = idx >> 6, c = idx & 63;
        Sr[r][c] = Pr[(size_t)r*N + c];
        Sc[r][c] = Pc[(size_t)r*N + c];
    }
    __syncthreads();
    int tx = tid & 15, ty = tid >> 4;
    float acc[4][4] = {};
    #pragma unroll 8
    for (int p = 0; p < 64; ++p) {
        float ar[4], ac[4];
        #pragma unroll
        for (int q = 0; q < 4; ++q) { ar[q] = Sr[ty*4+q][p]; ac[q] = Sc[tx*4+q][p]; }
        #pragma unroll
        for (int q = 0; q < 4; ++q)
            #pragma unroll
            for (int w = 0; w < 4; ++w) acc[q][w] = fmaf(ar[q], ac[w], acc[q][w]);
    }
    float* Out = A + (size_t)(t0 + bi*64)*N + (t0 + bj*64);
    #pragma unroll
    for (int q = 0; q < 4; ++q)
        #pragma unroll
        for (int w = 0; w < 4; ++w)
            Out[(size_t)(ty*4+q)*N + tx*4+w] -= acc[q][w];
    __syncthreads();
}

__device__ void tinv_body(float* __restrict__ ws, float* __restrict__ smem, int e, int j, int d, int tid) {
    int i = j + d;
    const float* L = ws + OFF_A  + (size_t)e*N*N;
    float*       W = ws + OFF_IK + (size_t)e*N*N;
    float (*Sa)[65] = (float(*)[65])smem;
    float (*Sb)[65] = (float(*)[65])(smem + 4160);
    float (*T )[65] = (float(*)[65])(smem + 8320);
    int tx = tid & 15, ty = tid >> 4;
    float acc[4][4] = {};
    for (int k = j; k < i; ++k) {
        __syncthreads();
        for (int idx = tid; idx < 4096; idx += 256) {
            int r = idx >> 6, cc = idx & 63;
            Sa[r][cc] = L[(size_t)(i*64+r)*N + k*64+cc];
            Sb[r][cc] = W[(size_t)(k*64+r)*N + j*64+cc];
        }
        __syncthreads();
        #pragma unroll 8
        for (int p = 0; p < 64; ++p) {
            float ar[4], ac[4];
            #pragma unroll
            for (int q = 0; q < 4; ++q) { ar[q] = Sa[ty*4+q][p]; ac[q] = Sb[p][tx*4+q]; }
            #pragma unroll
            for (int q = 0; q < 4; ++q)
                #pragma unroll
                for (int w = 0; w < 4; ++w) acc[q][w] = fmaf(ar[q], ac[w], acc[q][w]);
        }
    }
    __syncthreads();
    #pragma unroll
    for (int q = 0; q < 4; ++q)
        #pragma unroll
        for (int w = 0; w < 4; ++w) T[ty*4+q][tx*4+w] = acc[q][w];
    for (int idx = tid; idx < 4096; idx += 256) {
        int r = idx >> 6, cc = idx & 63;
        Sa[r][cc] = W[(size_t)(i*64+r)*N + i*64+cc];   // W_ii
    }
    __syncthreads();
    float o[4][4] = {};
    #pragma unroll 8
    for (int p = 0; p < 64; ++p) {
        float ar[4], ac[4];
        #pragma unroll
        for (int q = 0; q < 4; ++q) { ar[q] = Sa[ty*4+q][p]; ac[q] = T[p][tx*4+q]; }
        #pragma unroll
        for (int q = 0; q < 4; ++q)
            #pragma unroll
            for (int w = 0; w < 4; ++w) o[q][w] = fmaf(ar[q], ac[w], o[q][w]);
    }
    #pragma unroll
    for (int q = 0; q < 4; ++q)
        #pragma unroll
        for (int w = 0; w < 4; ++w)
            W[(size_t)(i*64+ty*4+q)*N + j*64+tx*4+w] = -o[q][w];
    __syncthreads();
}

__device__ void syrk_body(float* __restrict__ ws, float* __restrict__ smem, int task, int tid) {
    int e = task / 36;
    int t = task % 36;
    int bj = 0; while (t >= 8 - bj) { t -= 8 - bj; ++bj; }
    int bi = bj + t;                       // bi >= bj
    const float* W = ws + OFF_IK + (size_t)e*N*N;
    float*      IK = ws + OFF_A  + (size_t)e*N*N;
    float (*Sa)[65] = (float(*)[65])smem;
    float (*Sb)[65] = (float(*)[65])(smem + 4160);
    int tx = tid & 15, ty = tid >> 4;
    float acc[4][4] = {};
    for (int p = bi; p < 8; ++p) {
        __syncthreads();
        for (int idx = tid; idx < 4096; idx += 256) {
            int r = idx >> 6, cc = idx & 63;
            Sa[r][cc] = W[(size_t)(p*64+r)*N + bi*64+cc];
            Sb[r][cc] = W[(size_t)(p*64+r)*N + bj*64+cc];
        }
        __syncthreads();
        #pragma unroll 8
        for (int pr = 0; pr < 64; ++pr) {
            float ar[4], ac[4];
            #pragma unroll
            for (int q = 0; q < 4; ++q) { ar[q] = Sa[pr][ty*4+q]; ac[q] = Sb[pr][tx*4+q]; }
            #pragma unroll
            for (int q = 0; q < 4; ++q)
                #pragma unroll
                for (int w = 0; w < 4; ++w) acc[q][w] = fmaf(ar[q], ac[w], acc[q][w]);
        }
    }
    #pragma unroll
    for (int q = 0; q < 4; ++q)
        #pragma unroll
        for (int w = 0; w < 4; ++w) {
            int r = bi*64 + ty*4 + q, c = bj*64 + tx*4 + w;
            IK[(size_t)r*N + c] = acc[q][w];
            IK[(size_t)c*N + r] = acc[q][w];
        }
    __syncthreads();
}

__device__ void beta_body(float* __restrict__ ws, float* __restrict__ smem, int task, int tid) {
    int e = task >> 1, half = task & 1;
    int n = half*256 + tid;
    float* yn = smem;
    __syncthreads();
    for (int i = tid; i < N; i += 256) yn[i] = ws[OFF_YN + (size_t)e*N + i];
    __syncthreads();
    const float* IK = ws + OFF_A + (size_t)e*N*N;
    float a0 = 0.f, a1 = 0.f, a2 = 0.f, a3 = 0.f;
    for (int mm = 0; mm < N; mm += 4) {
        a0 = fmaf(IK[(size_t)mm*N + n],     yn[mm],   a0);
        a1 = fmaf(IK[(size_t)(mm+1)*N + n], yn[mm+1], a1);
        a2 = fmaf(IK[(size_t)(mm+2)*N + n], yn[mm+2], a2);
        a3 = fmaf(IK[(size_t)(mm+3)*N + n], yn[mm+3], a3);
    }
    ws[OFF_BETA + e*N + n] = (a0 + a1) + (a2 + a3);
    __syncthreads();
}

// cooperative: blocked Cholesky + triangular inverse + iK = W^T W + beta
__global__ __launch_bounds__(256) void k_factor(float* __restrict__ ws) {
    cg::grid_group grid = cg::this_grid();
    int bid = blockIdx.x;
    int G = gridDim.x;
    int tid = threadIdx.x;
    __shared__ float smem[12480];

    for (int kk = 0; kk < 8; ++kk) {
        int k0 = kk*64;
        if (bid < E) diag_body(ws, smem, bid, k0, tid);
        grid.sync();
        int nb = 7 - kk;
        if (nb > 0) {
            for (int t = bid; t < E*nb; t += G) panel_body(ws, smem, t / nb, t % nb, k0, tid);
            grid.sync();
            int nt = nb*(nb+1)/2;
            for (int t = bid; t < E*nt; t += G) trail_body(ws, smem, t, k0, tid);
            grid.sync();
        }
    }
    for (int d = 1; d < 8; ++d) {
        int w = 8 - d;
        for (int t = bid; t < E*w; t += G) tinv_body(ws, smem, t / w, t % w, d, tid);
        grid.sync();
    }
    for (int t = bid; t < E*36; t += G) syrk_body(ws, smem, t, tid);
    grid.sync();
    for (int t = bid; t < E*2; t += G) beta_body(ws, smem, t, tid);
}

// ---------- 4a. B inverse + detB -> c ----------
__global__ __launch_bounds__(256) void k_B(float* __restrict__ ws, const float* __restrict__ ls,
                                           const float* __restrict__ os) {
    int e = blockIdx.x;
    int tid = threadIdx.x;
    int i = tid >> 4, j = tid & 15;
    __shared__ float Bm[16][17], Inv[16][17];
    float li = ls[e*D + i], lj = ls[e*D + j];
    Bm[i][j] = ws[OFF_SSM + i*D + j] / (li*lj) + ((i==j) ? 1.f : 0.f);
    Inv[i][j] = (i==j) ? 1.f : 0.f;
    __syncthreads();
    float det = 1.f;
    for (int k = 0; k < D; ++k) {
        float p   = Bm[k][k];
        float fik = Bm[i][k];
        float bkj = Bm[k][j];
        float ikj = Inv[k][j];
        __syncthreads();
        det *= p;
        if (i == k) { Bm[k][j] = bkj/p; Inv[k][j] = ikj/p; }
        else        { float f = fik/p; Bm[i][j] -= f*bkj; Inv[i][j] -= f*ikj; }
        __syncthreads();
    }
    ws[OFF_BINV + ((size_t)e*D + i)*D + j] = Inv[i][j];
    if (tid == 0) ws[OFF_C + e] = os[e] / sqrtf(det);
}

// ---------- 4b. R inverse, detR, Q = R^{-1} ss / 2 ----------
__global__ __launch_bounds__(256) void k_R(float* __restrict__ ws, const float* __restrict__ ls) {
    int pair = blockIdx.x;           // E*E
    int a = pair / E, b = pair % E;
    int tid = threadIdx.x;
    int i = tid >> 4, j = tid & 15;
    __shared__ float Rm[16][17], Inv[16][17], ssl[16][17];
    float la = ls[a*D + j], lb2 = ls[b*D + j];
    float rj = 1.f/(la*la) + 1.f/(lb2*lb2);
    float ssv = ws[OFF_SSM + i*D + j];
    ssl[i][j] = ssv;
    Rm[i][j] = ssv * rj + ((i==j) ? 1.f : 0.f);
    Inv[i][j] = (i==j) ? 1.f : 0.f;
    __syncthreads();
    float det = 1.f;
    for (int k = 0; k < D; ++k) {
        float p   = Rm[k][k];
        float fik = Rm[i][k];
        float rkj = Rm[k][j];
        float ikj = Inv[k][j];
        __syncthreads();
        det *= p;
        if (i == k) { Rm[k][j] = rkj/p; Inv[k][j] = ikj/p; }
        else        { float f = fik/p; Rm[i][j] -= f*rkj; Inv[i][j] -= f*ikj; }
        __syncthreads();
    }
    float q = 0.f;
    #pragma unroll
    for (int k2 = 0; k2 < D; ++k2) q += Inv[i][k2] * ssl[k2][j];
    ws[OFF_Q + ((size_t)pair*D + i)*D + j] = 0.5f * q;
    if (tid == 0) ws[OFF_ISDR + pair] = 1.f / sqrtf(det);
}

// ---------- 5. per (e,n): iN, t, lb, tiL, kvec, X1 ----------
__global__ __launch_bounds__(256) void k_point(float* __restrict__ ws, const float* __restrict__ ls,
                                               const float* __restrict__ os) {
    int t = blockIdx.x*256 + threadIdx.x;   // E*N
    int e = t >> 9, n = t & 511;
    float iN[D], tt[D], l[D];
    #pragma unroll
    for (int d = 0; d < D; ++d) { l[d] = ls[e*D + d]; iN[d] = ws[OFF_INP + n*D + d] / l[d]; }
    #pragma unroll
    for (int d = 0; d < D; ++d) {
        float acc = 0.f;
        #pragma unroll
        for (int j = 0; j < D; ++j) acc += ws[OFF_BINV + ((size_t)e*D + d)*D + j] * iN[j];
        tt[d] = acc;
    }
    float siNt = 0.f, siN2 = 0.f;
    #pragma unroll
    for (int d = 0; d < D; ++d) { siNt += iN[d]*tt[d]; siN2 += iN[d]*iN[d]; }
    float lbv = __expf(-0.5f * siNt) * ws[OFF_BETA + e*N + n];
    ws[OFF_LB + e*N + n] = lbv;
    #pragma unroll
    for (int d = 0; d < D; ++d) ws[OFF_TIL + ((size_t)e*N + n)*D + d] = tt[d] / l[d];
    ws[OFF_KVEC + e*N + n] = logf(os[e]) - 0.5f * siN2;
    #pragma unroll
    for (int d = 0; d < D; ++d) ws[OFF_X1 + ((size_t)e*N + n)*D + d] = ws[OFF_INP + n*D + d] / (l[d]*l[d]);
}

// ---------- 6. X1Q, Xs_, X2s per (a,b,n) ----------
__global__ __launch_bounds__(256) void k_x1q(float* __restrict__ ws) {
    int t = blockIdx.x*256 + threadIdx.x;   // E*E*N
    int pair = t / N, n = t % N;
    int a = pair / E, b = pair % E;
    __shared__ float Qs[16][16];
    Qs[threadIdx.x >> 4][threadIdx.x & 15] = ws[OFF_Q + (size_t)pair*D*D + threadIdx.x];
    __syncthreads();
    float x1a[D], x1b[D];
    #pragma unroll
    for (int d = 0; d < D; ++d) {
        x1a[d] = ws[OFF_X1 + ((size_t)a*N + n)*D + d];
        x1b[d] = ws[OFF_X1 + ((size_t)b*N + n)*D + d];
    }
    float xs1 = 0.f, xs2 = 0.f;
    #pragma unroll
    for (int j = 0; j < D; ++j) {
        float acc = 0.f, acc2 = 0.f;
        #pragma unroll
        for (int i = 0; i < D; ++i) { acc += x1a[i]*Qs[i][j]; acc2 += x1b[i]*Qs[i][j]; }
        ws[OFF_X1Q + ((size_t)pair*N + n)*D + j] = acc;
        xs1 += acc  * x1a[j];
        xs2 += acc2 * x1b[j];
    }
    ws[OFF_XS1 + (size_t)pair*N + n] = xs1;
    ws[OFF_XS2 + (size_t)pair*N + n] = xs2;
}

// ---------- 7. big cross-term, 64x64 tiles, 4x4 register blocking ----------
__global__ __launch_bounds__(256) void k_S(float* __restrict__ ws) {
    int bid = blockIdx.x;            // E*E*8
    int pair = bid >> 3, ntile = bid & 7;
    int a = pair / E, b = pair % E;
    int tid = threadIdx.x;
    int tx = tid & 15, ty = tid >> 4;
    __shared__ float x1q[64][17], x2t[64][17];
    __shared__ float u[64], v[64], ba[64], bb[64];
    __shared__ float red[256];
    int n0 = ntile*64;
    for (int idx = tid; idx < 1024; idx += 256) {
        int r = idx >> 4, d = idx & 15;
        x1q[r][d] = ws[OFF_X1Q + ((size_t)pair*N + n0 + r)*D + d];
    }
    if (tid < 64) {
        int nn = n0 + tid;
        u[tid]  = ws[OFF_KVEC + a*N + nn] + ws[OFF_XS1 + (size_t)pair*N + nn];
        ba[tid] = ws[OFF_BETA + a*N + nn];
    }
    float sacc = 0.f, tacc = 0.f;
    for (int mt = 0; mt < 8; ++mt) {
        __syncthreads();
        for (int idx = tid; idx < 1024; idx += 256) {
            int r = idx >> 4, d = idx & 15;
            x2t[r][d] = ws[OFF_X1 + ((size_t)b*N + mt*64 + r)*D + d];
        }
        if (tid < 64) {
            int mm = mt*64 + tid;
            v[tid]  = ws[OFF_KVEC + b*N + mm] + ws[OFF_XS2 + (size_t)pair*N + mm];
            bb[tid] = ws[OFF_BETA + b*N + mm];
        }
        __syncthreads();
        float dacc[4][4] = {};
        #pragma unroll
        for (int d = 0; d < 16; ++d) {
            float av[4], bv[4];
            #pragma unroll
            for (int q = 0; q < 4; ++q) av[q] = x1q[ty*4+q][d];
            #pragma unroll
            for (int w = 0; w < 4; ++w) bv[w] = x2t[tx*4+w][d];
            #pragma unroll
            for (int q = 0; q < 4; ++q)
                #pragma unroll
                for (int w = 0; w < 4; ++w)
                    dacc[q][w] = fmaf(av[q], bv[w], dacc[q][w]);
        }
        #pragma unroll
        for (int q = 0; q < 4; ++q) {
            float uq = u[ty*4+q], baq = ba[ty*4+q];
            #pragma unroll
            for (int w = 0; w < 4; ++w) {
                float Lv = __expf(2.f*dacc[q][w] + uq + v[tx*4+w]);
                sacc = fmaf(baq * bb[tx*4+w], Lv, sacc);
                if (a == b) {
                    float ik = ws[OFF_A + ((size_t)a*N + n0 + ty*4 + q)*N + mt*64 + tx*4 + w];
                    tacc = fmaf(ik, Lv, tacc);
                }
            }
        }
    }
    red[tid] = sacc; __syncthreads();
    for (int o = 128; o > 0; o >>= 1) { if (tid < o) red[tid] += red[tid+o]; __syncthreads(); }
    if (tid == 0) ws[OFF_SPART + bid] = red[0];
    if (a == b) {
        __syncthreads();
        red[tid] = tacc; __syncthreads();
        for (int o = 128; o > 0; o >>= 1) { if (tid < o) red[tid] += red[tid+o]; __syncthreads(); }
        if (tid == 0) ws[OFF_TPART + a*8 + ntile] = red[0];
    }
}

// ---------- 8. finalize ----------
__global__ __launch_bounds__(256) void k_final(float* __restrict__ ws, const float* __restrict__ s,
                                               const float* __restrict__ os, float* __restrict__ out) {
    int tid = threadIdx.x;  // 256
    __shared__ float red[256];
    __shared__ float Msh[E], Vsh[E][D], cov[D][E+1];
    __shared__ float Sm[16][17], Si[16][17];

    for (int e = 0; e < E; ++e) {
        float p = 0.f;
        for (int n = tid; n < N; n += 256) p += ws[OFF_LB + e*N + n];
        red[tid] = p; __syncthreads();
        for (int o = 128; o > 0; o >>= 1) { if (tid < o) red[tid] += red[tid+o]; __syncthreads(); }
        if (tid == 0) Msh[e] = ws[OFF_C + e] * red[0];
        __syncthreads();
    }
    if (tid < E*D) {
        int e = tid / D, d = tid % D;
        float acc = 0.f;
        for (int n = 0; n < N; ++n)
            acc += ws[OFF_TIL + ((size_t)e*N + n)*D + d] * ws[OFF_LB + e*N + n];
        Vsh[e][d] = ws[OFF_C + e] * acc;
    }
    __syncthreads();

    if (tid < E*E) {
        int a = tid / E, bb = tid % E;
        float acc = 0.f;
        for (int q = 0; q < 8; ++q) acc += ws[OFF_SPART + (size_t)tid*8 + q];
        if (a == bb) {
            float tr = 0.f;
            for (int q = 0; q < 8; ++q) tr += ws[OFF_TPART + a*8 + q];
            acc -= tr;
        }
        acc *= ws[OFF_ISDR + tid];
        if (a == bb) acc += os[a];
        float v = acc - Msh[a]*Msh[bb];
        v *= ws[OFF_YSTD + a] * ws[OFF_YSTD + bb];
        out[E + tid] = v;                                // S
    }
    if (tid < E) out[tid] = Msh[tid]*ws[OFF_YSTD + tid] + ws[OFF_YMEAN + tid];  // Mout

    if (tid < D*E) {
        int d = tid / E, e = tid % E;
        float acc = 0.f;
        for (int k = 0; k < D; ++k) acc += ws[OFF_SSM + d*D + k] * Vsh[e][k];
        cov[d][e] = acc * ws[OFF_XSTD + d] * ws[OFF_YSTD + e];
    }
    int i = tid >> 4, j = tid & 15;
    Sm[i][j] = s[i*D + j];
    Si[i][j] = (i==j) ? 1.f : 0.f;
    __syncthreads();
    for (int k = 0; k < D; ++k) {
        float p   = Sm[k][k];
        float fik = Sm[i][k];
        float skj = Sm[k][j];
        float ikj = Si[k][j];
        __syncthreads();
        if (i == k) { Sm[k][j] = skj/p; Si[k][j] = ikj/p; }
        else        { float f = fik/p; Sm[i][j] -= f*skj; Si[i][j] -= f*ikj; }
        __syncthreads();
    }
    if (tid < D*E) {
        int d = tid / E, e = tid % E;
        float acc = 0.f;
        for (int k = 0; k < D; ++k) acc += Si[d][k] * cov[k][e];
        out[E + E*E + d*E + e] = acc;                    // Vout
    }
}

extern "C" void kernel_launch(void* const* d_in, const int* in_sizes, int n_in,
                              void* d_out, int out_size, void* d_ws, size_t ws_size,
                              hipStream_t stream) {
    const float* X     = (const float*)d_in[0];
    const float* Y     = (const float*)d_in[1];
    const float* m     = (const float*)d_in[2];
    const float* s     = (const float*)d_in[3];
    const float* ls    = (const float*)d_in[4];
    const float* os    = (const float*)d_in[5];
    const float* noise = (const float*)d_in[6];
    float* ws  = (float*)d_ws;
    float* out = (float*)d_out;

    k_prep  <<<1,    512, 0, stream>>>(X, Y, m, s, ws);
    k_buildA<<<E*64, 256, 0, stream>>>(ws, ls, os, noise);

    void* args[] = { (void*)&ws };
    hipLaunchCooperativeKernel((void*)k_factor, dim3(432), dim3(256), args, 0, stream);

    k_B    <<<E,         256, 0, stream>>>(ws, ls, os);
    k_R    <<<E*E,       256, 0, stream>>>(ws, ls);
    k_point<<<E*N/256,   256, 0, stream>>>(ws, ls, os);
    k_x1q  <<<E*E*N/256, 256, 0, stream>>>(ws);
    k_S    <<<E*E*8,     256, 0, stream>>>(ws);
    k_final<<<1,         256, 0, stream>>>(ws, s, os, out);
}

// Round 6
// 938.919 us; speedup vs baseline: 2.2736x; 2.2736x over previous
//
#include <hip/hip_runtime.h>
#include <math.h>

constexpr int N = 512;
constexpr int D = 16;
constexpr int E = 12;

// ---- workspace layout (float offsets) ----
constexpr size_t OFF_A     = 0;                            // E*N*N  A -> L -> iK
constexpr size_t OFF_IK    = OFF_A    + (size_t)E*N*N;     // E*N*N  W = L^{-1}
constexpr size_t OFF_XS    = OFF_IK   + (size_t)E*N*N;     // N*D
constexpr size_t OFF_INP   = OFF_XS   + (size_t)N*D;       // N*D
constexpr size_t OFF_YN    = OFF_INP  + (size_t)N*D;       // E*N
constexpr size_t OFF_BETA  = OFF_YN   + (size_t)E*N;       // E*N
constexpr size_t OFF_KVEC  = OFF_BETA + (size_t)E*N;       // E*N
constexpr size_t OFF_LB    = OFF_KVEC + (size_t)E*N;       // E*N
constexpr size_t OFF_TIL   = OFF_LB   + (size_t)E*N;       // E*N*D
constexpr size_t OFF_Q     = OFF_TIL  + (size_t)E*N*D;     // E*E*D*D
constexpr size_t OFF_BINV  = OFF_Q    + (size_t)E*E*D*D;   // E*D*D
constexpr size_t OFF_C     = OFF_BINV + (size_t)E*D*D;     // E
constexpr size_t OFF_ISDR  = OFF_C    + E;                 // E*E
constexpr size_t OFF_SPART = OFF_ISDR + E*E;               // E*E*8
constexpr size_t OFF_TPART = OFF_SPART+ (size_t)E*E*8;     // E*8
constexpr size_t OFF_XMEAN = OFF_TPART+ (size_t)E*8;       // D
constexpr size_t OFF_XSTD  = OFF_XMEAN+ D;                 // D
constexpr size_t OFF_YMEAN = OFF_XSTD + D;                 // E
constexpr size_t OFF_YSTD  = OFF_YMEAN+ E;                 // E
constexpr size_t OFF_SSM   = OFF_YSTD + E;                 // D*D

// ---------- 1. standardization ----------
__global__ __launch_bounds__(512) void k_prep(const float* __restrict__ X, const float* __restrict__ Y,
                                              const float* __restrict__ m, const float* __restrict__ s,
                                              float* __restrict__ ws) {
    int tid = threadIdx.x;
    int lane = tid & 63, wave = tid >> 6;   // 8 waves
    __shared__ float meanX[D], stdX[D], meanY[E], stdY[E], mmsh[D];

    for (int col = wave; col < D + E; col += 8) {
        float s1 = 0.f, s2 = 0.f;
        if (col < D) {
            #pragma unroll
            for (int i = 0; i < 8; ++i) { float v = X[(i*64 + lane)*D + col]; s1 += v; s2 += v*v; }
        } else {
            int e = col - D;
            #pragma unroll
            for (int i = 0; i < 8; ++i) { float v = Y[(i*64 + lane)*E + e]; s1 += v; s2 += v*v; }
        }
        #pragma unroll
        for (int off = 32; off > 0; off >>= 1) { s1 += __shfl_xor(s1, off); s2 += __shfl_xor(s2, off); }
        if (lane == 0) {
            float mean = s1 * (1.0f/N);
            float var  = (s2 - (float)N*mean*mean) * (1.0f/(N-1));
            float sd   = sqrtf(var);
            if (col < D) { meanX[col] = mean; stdX[col] = sd; }
            else         { meanY[col-D] = mean; stdY[col-D] = sd; }
        }
    }
    __syncthreads();
    if (tid < D) {
        mmsh[tid] = (m[tid] - meanX[tid]) / stdX[tid];
        ws[OFF_XMEAN + tid] = meanX[tid];
        ws[OFF_XSTD  + tid] = stdX[tid];
    }
    if (tid < E) { ws[OFF_YMEAN + tid] = meanY[tid]; ws[OFF_YSTD + tid] = stdY[tid]; }
    __syncthreads();
    int n = tid;
    #pragma unroll
    for (int d = 0; d < D; ++d) {
        float xs = (X[n*D + d] - meanX[d]) / stdX[d];
        ws[OFF_XS  + n*D + d] = xs;
        ws[OFF_INP + n*D + d] = xs - mmsh[d];
    }
    #pragma unroll
    for (int e = 0; e < E; ++e)
        ws[OFF_YN + e*N + n] = (Y[n*E + e] - meanY[e]) / stdY[e];
    if (tid < D*D) {
        int i = tid / D, j = tid % D;
        ws[OFF_SSM + tid] = s[tid] / (stdX[i] * stdX[j]);
    }
}

// ---------- 2. A = K + noise I (64x64 tiles) ----------
__global__ __launch_bounds__(256) void k_buildA(float* __restrict__ ws, const float* __restrict__ ls,
                                                const float* __restrict__ os, const float* __restrict__ noise) {
    int bid = blockIdx.x;            // E * 8 * 8
    int e  = bid >> 6;
    int t  = bid & 63;
    int bn = t >> 3, bm = t & 7;
    int tid = threadIdx.x;
    __shared__ float xn[64][17], xm[64][17];
    __shared__ float il2[16];
    for (int idx = tid; idx < 1024; idx += 256) {
        int r = idx >> 4, d0 = idx & 15;
        xn[r][d0] = ws[OFF_XS + (size_t)(bn*64 + r)*D + d0];
        xm[r][d0] = ws[OFF_XS + (size_t)(bm*64 + r)*D + d0];
    }
    if (tid < 16) { float l = ls[e*D + tid]; il2[tid] = 1.0f/(l*l); }
    __syncthreads();
    int tx = tid & 15, ty = tid >> 4;
    float osv = os[e], nsv = noise[e];
    float acc[4][4] = {};
    #pragma unroll
    for (int d = 0; d < 16; ++d) {
        float il = il2[d];
        float an[4], am[4];
        #pragma unroll
        for (int q = 0; q < 4; ++q) { an[q] = xn[ty + q*16][d]; am[q] = xm[tx + q*16][d]; }
        #pragma unroll
        for (int q = 0; q < 4; ++q)
            #pragma unroll
            for (int w = 0; w < 4; ++w) { float df = an[q] - am[w]; acc[q][w] = fmaf(df*df, il, acc[q][w]); }
    }
    float* A = ws + OFF_A + (size_t)e*N*N;
    #pragma unroll
    for (int q = 0; q < 4; ++q)
        #pragma unroll
        for (int w = 0; w < 4; ++w) {
            int nr = bn*64 + ty + q*16, mc = bm*64 + tx + w*16;
            float v = osv * __expf(-0.5f * acc[q][w]);
            if (nr == mc) v += nsv;
            A[(size_t)nr*N + mc] = v;
        }
}

// ---------- 3a. standalone 64x64 Cholesky + inverse for k0=0 (round-4 verified) ----------
__global__ __launch_bounds__(64) void k_diag64(float* __restrict__ ws, int k0) {
    int e = blockIdx.x;
    int lane = threadIdx.x;
    const float* A = ws + OFF_A + (size_t)e*N*N;
    float* W = ws + OFF_IK + (size_t)e*N*N;
    __shared__ float __align__(16) Lsh[64][68];
    __shared__ float colbuf[64];
    __shared__ float invdsh[64];

    float a[64];
    #pragma unroll
    for (int c = 0; c < 64; ++c) a[c] = A[(size_t)(k0 + c)*N + k0 + lane];

    #pragma unroll
    for (int k = 0; k < 64; ++k) {
        colbuf[lane] = a[k];
        __syncthreads();
        float dkk = colbuf[k];
        float dv = sqrtf(dkk), iv = 1.0f/dv;
        if (lane == k) { a[k] = dv; invdsh[k] = iv; }
        else if (lane > k) a[k] *= iv;
        colbuf[lane] = a[k];
        __syncthreads();
        float lrk = a[k];
        #pragma unroll
        for (int c = k + 1; c < 64; ++c)
            a[c] = fmaf(-lrk, colbuf[c], a[c]);
        __syncthreads();
    }
    #pragma unroll
    for (int c4 = 0; c4 < 16; ++c4) {
        float4 v; v.x = a[c4*4]; v.y = a[c4*4+1]; v.z = a[c4*4+2]; v.w = a[c4*4+3];
        *(float4*)&Lsh[lane][c4*4] = v;
    }
    // write L rows to global (upper garbage harmless)
    float* Aw = ws + OFF_A + (size_t)e*N*N;
    #pragma unroll
    for (int c = 0; c < 64; ++c) Aw[(size_t)(k0 + lane)*N + k0 + c] = a[c];
    __syncthreads();

    float x[64];
    int c = lane;
    #pragma unroll
    for (int r = 0; r < 64; ++r) {
        float acc0 = (r == c) ? 1.0f : 0.0f, acc1 = 0.f, acc2 = 0.f, acc3 = 0.f;
        #pragma unroll
        for (int k4 = 0; k4 < (r >> 2); ++k4) {
            float4 L4 = *(const float4*)&Lsh[r][k4*4];
            acc0 = fmaf(-L4.x, x[k4*4+0], acc0);
            acc1 = fmaf(-L4.y, x[k4*4+1], acc1);
            acc2 = fmaf(-L4.z, x[k4*4+2], acc2);
            acc3 = fmaf(-L4.w, x[k4*4+3], acc3);
        }
        #pragma unroll
        for (int k = r & ~3; k < r; ++k)
            acc0 = fmaf(-Lsh[r][k], x[k], acc0);
        x[r] = ((acc0 + acc1) + (acc2 + acc3)) * invdsh[r];
    }
    #pragma unroll
    for (int r = 0; r < 64; ++r)
        W[(size_t)(k0 + r)*N + k0 + c] = x[r];
}

// ---------- 3b. panel TRSM as GEMM: P <- P * W_kk^T ----------
__global__ __launch_bounds__(256) void k_panelmul(float* __restrict__ ws, int k0) {
    int nb = (N - k0 - 64) >> 6;
    int e  = blockIdx.x / nb;
    int bi = blockIdx.x % nb;
    float* A = ws + OFF_A + (size_t)e*N*N;
    const float* W = ws + OFF_IK + (size_t)e*N*N;
    int r0 = k0 + 64 + bi*64;
    __shared__ float Ps[64][65], Wsh[64][65];
    int tid = threadIdx.x;
    for (int idx = tid; idx < 4096; idx += 256) {
        int r = idx >> 6, c2 = idx & 63;
        Ps[r][c2]  = A[(size_t)(r0 + r)*N + k0 + c2];
        Wsh[r][c2] = W[(size_t)(k0 + r)*N + k0 + c2];
    }
    __syncthreads();
    int tx = tid & 15, ty = tid >> 4;
    float acc[4][4] = {};
    #pragma unroll 8
    for (int j = 0; j < 64; ++j) {
        float pr[4], wr[4];
        #pragma unroll
        for (int q = 0; q < 4; ++q) { pr[q] = Ps[ty*4+q][j]; wr[q] = Wsh[tx*4+q][j]; }
        #pragma unroll
        for (int q = 0; q < 4; ++q)
            #pragma unroll
            for (int w = 0; w < 4; ++w) acc[q][w] = fmaf(pr[q], wr[w], acc[q][w]);
    }
    __syncthreads();
    #pragma unroll
    for (int q = 0; q < 4; ++q)
        #pragma unroll
        for (int w = 0; w < 4; ++w)
            A[(size_t)(r0 + ty*4 + q)*N + k0 + tx*4 + w] = acc[q][w];
}

// ---------- 3c. trailing SYRK update + FUSED next-diag factor+inverse on tile (0,0) ----------
__global__ __launch_bounds__(256) void k_traild(float* __restrict__ ws, int k0) {
    int t0 = k0 + 64;
    int nb = (N - t0) >> 6;
    int ntiles = (nb*(nb+1)) >> 1;
    int e = blockIdx.x / ntiles;
    int t = blockIdx.x % ntiles;
    int bj = 0; while (t >= nb - bj) { t -= nb - bj; ++bj; }
    int bi = bj + t;
    bool isdiag = (bi == 0) && (bj == 0);
    float* A = ws + OFF_A + (size_t)e*N*N;
    const float* Pr = A + (size_t)(t0 + bi*64)*N + k0;
    const float* Pc = A + (size_t)(t0 + bj*64)*N + k0;
    __shared__ float Sr[64][65], Sc[64][65];
    __shared__ float __align__(16) Lsh[64][68];
    __shared__ float colbuf[64], invdsh[64];
    int tid = threadIdx.x;
    for (int idx = tid; idx < 4096; idx += 256) {
        int r = idx >> 6, c = idx & 63;
        Sr[r][c] = Pr[(size_t)r*N + c];
        Sc[r][c] = Pc[(size_t)r*N + c];
    }
    __syncthreads();
    int tx = tid & 15, ty = tid >> 4;
    float acc[4][4] = {};
    #pragma unroll 8
    for (int p = 0; p < 64; ++p) {
        float ar[4], ac[4];
        #pragma unroll
        for (int q = 0; q < 4; ++q) { ar[q] = Sr[ty*4+q][p]; ac[q] = Sc[tx*4+q][p]; }
        #pragma unroll
        for (int q = 0; q < 4; ++q)
            #pragma unroll
            for (int w = 0; w < 4; ++w) acc[q][w] = fmaf(ar[q], ac[w], acc[q][w]);
    }
    float* Out = A + (size_t)(t0 + bi*64)*N + (t0 + bj*64);
    if (!isdiag) {
        #pragma unroll
        for (int q = 0; q < 4; ++q)
            #pragma unroll
            for (int w = 0; w < 4; ++w)
                Out[(size_t)(ty*4+q)*N + tx*4+w] -= acc[q][w];
        return;
    }
    // ---- fused: finish the next diag block and factor+invert it ----
    __syncthreads();   // all Sr/Sc reads done before overwrite
    #pragma unroll
    for (int q = 0; q < 4; ++q)
        #pragma unroll
        for (int w = 0; w < 4; ++w)
            Sr[ty*4+q][tx*4+w] = Out[(size_t)(ty*4+q)*N + tx*4+w] - acc[q][w];
    __syncthreads();

    bool act = tid < 64;
    int lane = tid;
    float a[64];
    if (act) {
        #pragma unroll
        for (int c = 0; c < 64; ++c) a[c] = Sr[c][lane];   // symmetric tile
    }
    #pragma unroll
    for (int k = 0; k < 64; ++k) {
        if (act && lane == k) {
            float dv = sqrtf(a[k]);
            a[k] = dv; colbuf[k] = dv; invdsh[k] = 1.0f/dv;
        }
        __syncthreads();
        if (act && lane > k) { a[k] *= invdsh[k]; colbuf[lane] = a[k]; }
        __syncthreads();
        if (act) {
            float lrk = a[k];
            #pragma unroll
            for (int c = k + 1; c < 64; ++c)
                a[c] = fmaf(-lrk, colbuf[c], a[c]);
        }
        __syncthreads();
    }
    if (act) {
        #pragma unroll
        for (int c4 = 0; c4 < 16; ++c4) {
            float4 v; v.x = a[c4*4]; v.y = a[c4*4+1]; v.z = a[c4*4+2]; v.w = a[c4*4+3];
            *(float4*)&Lsh[lane][c4*4] = v;
        }
        #pragma unroll
        for (int c = 0; c < 64; ++c)
            A[(size_t)(t0 + lane)*N + t0 + c] = a[c];     // L rows (upper garbage unused)
    }
    __syncthreads();
    if (act) {
        float* W = ws + OFF_IK + (size_t)e*N*N;
        float x[64];
        int c = lane;
        #pragma unroll
        for (int r = 0; r < 64; ++r) {
            float acc0 = (r == c) ? 1.0f : 0.0f, acc1 = 0.f, acc2 = 0.f, acc3 = 0.f;
            #pragma unroll
            for (int k4 = 0; k4 < (r >> 2); ++k4) {
                float4 L4 = *(const float4*)&Lsh[r][k4*4];
                acc0 = fmaf(-L4.x, x[k4*4+0], acc0);
                acc1 = fmaf(-L4.y, x[k4*4+1], acc1);
                acc2 = fmaf(-L4.z, x[k4*4+2], acc2);
                acc3 = fmaf(-L4.w, x[k4*4+3], acc3);
            }
            #pragma unroll
            for (int k = r & ~3; k < r; ++k)
                acc0 = fmaf(-Lsh[r][k], x[k], acc0);
            x[r] = ((acc0 + acc1) + (acc2 + acc3)) * invdsh[r];
        }
        #pragma unroll
        for (int r = 0; r < 64; ++r)
            W[(size_t)(t0 + r)*N + t0 + c] = x[r];
    }
}

// ---------- 3d. triangular inverse off-diagonal wavefront d ----------
__global__ __launch_bounds__(256) void k_tinv_off(float* __restrict__ ws, int d) {
    int e = blockIdx.x / (8 - d);
    int j = blockIdx.x % (8 - d);
    int i = j + d;
    const float* L = ws + OFF_A  + (size_t)e*N*N;
    float*       W = ws + OFF_IK + (size_t)e*N*N;
    __shared__ float Sa[64][65], Sb[64][65], T[64][65];
    int tid = threadIdx.x;
    int tx = tid & 15, ty = tid >> 4;
    float acc[4][4] = {};
    for (int k = j; k < i; ++k) {
        __syncthreads();
        for (int idx = tid; idx < 4096; idx += 256) {
            int r = idx >> 6, cc = idx & 63;
            Sa[r][cc] = L[(size_t)(i*64+r)*N + k*64+cc];
            Sb[r][cc] = W[(size_t)(k*64+r)*N + j*64+cc];
        }
        __syncthreads();
        #pragma unroll 8
        for (int p = 0; p < 64; ++p) {
            float ar[4], ac[4];
            #pragma unroll
            for (int q = 0; q < 4; ++q) { ar[q] = Sa[ty*4+q][p]; ac[q] = Sb[p][tx*4+q]; }
            #pragma unroll
            for (int q = 0; q < 4; ++q)
                #pragma unroll
                for (int w = 0; w < 4; ++w) acc[q][w] = fmaf(ar[q], ac[w], acc[q][w]);
        }
    }
    __syncthreads();
    #pragma unroll
    for (int q = 0; q < 4; ++q)
        #pragma unroll
        for (int w = 0; w < 4; ++w) T[ty*4+q][tx*4+w] = acc[q][w];
    for (int idx = tid; idx < 4096; idx += 256) {
        int r = idx >> 6, cc = idx & 63;
        Sa[r][cc] = W[(size_t)(i*64+r)*N + i*64+cc];   // W_ii
    }
    __syncthreads();
    float o[4][4] = {};
    #pragma unroll 8
    for (int p = 0; p < 64; ++p) {
        float ar[4], ac[4];
        #pragma unroll
        for (int q = 0; q < 4; ++q) { ar[q] = Sa[ty*4+q][p]; ac[q] = T[p][tx*4+q]; }
        #pragma unroll
        for (int q = 0; q < 4; ++q)
            #pragma unroll
            for (int w = 0; w < 4; ++w) o[q][w] = fmaf(ar[q], ac[w], o[q][w]);
    }
    #pragma unroll
    for (int q = 0; q < 4; ++q)
        #pragma unroll
        for (int w = 0; w < 4; ++w)
            W[(size_t)(i*64+ty*4+q)*N + j*64+tx*4+w] = -o[q][w];
}

// ---------- 3e. iK = W^T W (into OFF_A, full symmetric) ----------
__global__ __launch_bounds__(256) void k_syrk(float* __restrict__ ws) {
    int e = blockIdx.x / 36;
    int t = blockIdx.x % 36;
    int bj = 0; while (t >= 8 - bj) { t -= 8 - bj; ++bj; }
    int bi = bj + t;                       // bi >= bj
    const float* W = ws + OFF_IK + (size_t)e*N*N;
    float*      IK = ws + OFF_A  + (size_t)e*N*N;
    __shared__ float Sa[64][65], Sb[64][65];
    int tid = threadIdx.x;
    int tx = tid & 15, ty = tid >> 4;
    float acc[4][4] = {};
    for (int p = bi; p < 8; ++p) {
        __syncthreads();
        for (int idx = tid; idx < 4096; idx += 256) {
            int r = idx >> 6, cc = idx & 63;
            Sa[r][cc] = W[(size_t)(p*64+r)*N + bi*64+cc];
            Sb[r][cc] = W[(size_t)(p*64+r)*N + bj*64+cc];
        }
        __syncthreads();
        #pragma unroll 8
        for (int pr = 0; pr < 64; ++pr) {
            float ar[4], ac[4];
            #pragma unroll
            for (int q = 0; q < 4; ++q) { ar[q] = Sa[pr][ty*4+q]; ac[q] = Sb[pr][tx*4+q]; }
            #pragma unroll
            for (int q = 0; q < 4; ++q)
                #pragma unroll
                for (int w = 0; w < 4; ++w) acc[q][w] = fmaf(ar[q], ac[w], acc[q][w]);
        }
    }
    #pragma unroll
    for (int q = 0; q < 4; ++q)
        #pragma unroll
        for (int w = 0; w < 4; ++w) {
            int r = bi*64 + ty*4 + q, c = bj*64 + tx*4 + w;
            IK[(size_t)r*N + c] = acc[q][w];
            IK[(size_t)c*N + r] = acc[q][w];
        }
}

// ---------- 3f. beta = iK @ Yn (4 blocks per e, m-halves combined in LDS) ----------
__global__ __launch_bounds__(256) void k_beta(float* __restrict__ ws) {
    int e = blockIdx.x >> 2, qtr = blockIdx.x & 3;
    int tid = threadIdx.x;
    int half = tid >> 7;          // 0/1
    int nl = tid & 127;
    int n = qtr*128 + nl;
    __shared__ float yn[N];
    __shared__ float part[2][128];
    for (int i = tid; i < N; i += 256) yn[i] = ws[OFF_YN + (size_t)e*N + i];
    __syncthreads();
    const float* IK = ws + OFF_A + (size_t)e*N*N;
    int m0 = half*256;
    float a0 = 0.f, a1 = 0.f, a2 = 0.f, a3 = 0.f;
    for (int mm = m0; mm < m0 + 256; mm += 4) {
        a0 = fmaf(IK[(size_t)mm*N + n],     yn[mm],   a0);
        a1 = fmaf(IK[(size_t)(mm+1)*N + n], yn[mm+1], a1);
        a2 = fmaf(IK[(size_t)(mm+2)*N + n], yn[mm+2], a2);
        a3 = fmaf(IK[(size_t)(mm+3)*N + n], yn[mm+3], a3);
    }
    part[half][nl] = (a0 + a1) + (a2 + a3);
    __syncthreads();
    if (tid < 128)
        ws[OFF_BETA + e*N + qtr*128 + tid] = part[0][tid] + part[1][tid];
}

// ---------- 4. merged B inverse (+c) and R inverse (+Q, isdr) ----------
__global__ __launch_bounds__(256) void k_BR(float* __restrict__ ws, const float* __restrict__ ls,
                                            const float* __restrict__ os) {
    int bidx = blockIdx.x;
    int tid = threadIdx.x;
    int i = tid >> 4, j = tid & 15;
    if (bidx < E) {
        int e = bidx;
        __shared__ float Bm[16][17], Inv[16][17];
        float li = ls[e*D + i], lj = ls[e*D + j];
        Bm[i][j] = ws[OFF_SSM + i*D + j] / (li*lj) + ((i==j) ? 1.f : 0.f);
        Inv[i][j] = (i==j) ? 1.f : 0.f;
        __syncthreads();
        float det = 1.f;
        for (int k = 0; k < D; ++k) {
            float p   = Bm[k][k];
            float fik = Bm[i][k];
            float bkj = Bm[k][j];
            float ikj = Inv[k][j];
            __syncthreads();
            det *= p;
            if (i == k) { Bm[k][j] = bkj/p; Inv[k][j] = ikj/p; }
            else        { float f = fik/p; Bm[i][j] -= f*bkj; Inv[i][j] -= f*ikj; }
            __syncthreads();
        }
        ws[OFF_BINV + ((size_t)e*D + i)*D + j] = Inv[i][j];
        if (tid == 0) ws[OFF_C + e] = os[e] / sqrtf(det);
    } else {
        int pair = bidx - E;
        int a = pair / E, b = pair % E;
        __shared__ float Rm[16][17], Inv[16][17], ssl[16][17];
        float la = ls[a*D + j], lb2 = ls[b*D + j];
        float rj = 1.f/(la*la) + 1.f/(lb2*lb2);
        float ssv = ws[OFF_SSM + i*D + j];
        ssl[i][j] = ssv;
        Rm[i][j] = ssv * rj + ((i==j) ? 1.f : 0.f);
        Inv[i][j] = (i==j) ? 1.f : 0.f;
        __syncthreads();
        float det = 1.f;
        for (int k = 0; k < D; ++k) {
            float p   = Rm[k][k];
            float fik = Rm[i][k];
            float rkj = Rm[k][j];
            float ikj = Inv[k][j];
            __syncthreads();
            det *= p;
            if (i == k) { Rm[k][j] = rkj/p; Inv[k][j] = ikj/p; }
            else        { float f = fik/p; Rm[i][j] -= f*rkj; Inv[i][j] -= f*ikj; }
            __syncthreads();
        }
        float q = 0.f;
        #pragma unroll
        for (int k2 = 0; k2 < D; ++k2) q += Inv[i][k2] * ssl[k2][j];
        ws[OFF_Q + ((size_t)pair*D + i)*D + j] = 0.5f * q;
        if (tid == 0) ws[OFF_ISDR + pair] = 1.f / sqrtf(det);
    }
}

// ---------- 5. per (e,n): iN, t, lb, tiL, kvec ----------
__global__ __launch_bounds__(256) void k_point(float* __restrict__ ws, const float* __restrict__ ls,
                                               const float* __restrict__ os) {
    int t = blockIdx.x*256 + threadIdx.x;   // E*N
    int e = t >> 9, n = t & 511;
    float iN[D], tt[D], l[D];
    #pragma unroll
    for (int d = 0; d < D; ++d) { l[d] = ls[e*D + d]; iN[d] = ws[OFF_INP + n*D + d] / l[d]; }
    #pragma unroll
    for (int d = 0; d < D; ++d) {
        float acc = 0.f;
        #pragma unroll
        for (int j = 0; j < D; ++j) acc += ws[OFF_BINV + ((size_t)e*D + d)*D + j] * iN[j];
        tt[d] = acc;
    }
    float siNt = 0.f, siN2 = 0.f;
    #pragma unroll
    for (int d = 0; d < D; ++d) { siNt += iN[d]*tt[d]; siN2 += iN[d]*iN[d]; }
    float lbv = __expf(-0.5f * siNt) * ws[OFF_BETA + e*N + n];
    ws[OFF_LB + e*N + n] = lbv;
    #pragma unroll
    for (int d = 0; d < D; ++d) ws[OFF_TIL + ((size_t)e*N + n)*D + d] = tt[d] / l[d];
    ws[OFF_KVEC + e*N + n] = logf(os[e]) - 0.5f * siN2;
}

// ---------- 7. big cross-term with fused X1Q/XS1/XS2 (64x64 tiles, 4x4 blocking) ----------
__global__ __launch_bounds__(256) void k_S(float* __restrict__ ws, const float* __restrict__ ls) {
    int bid = blockIdx.x;            // E*E*8
    int pair = bid >> 3, ntile = bid & 7;
    int a = pair / E, b = pair % E;
    int tid = threadIdx.x;
    int tx = tid & 15, ty = tid >> 4;
    __shared__ float Qs[16][17];
    __shared__ float ils2a[16], ils2b[16];
    __shared__ float x1q[64][17], bufA[64][17], bufB[64][17];
    __shared__ float u[64], v[64], ba[64], bb[64];
    __shared__ float red[256];
    int n0 = ntile*64;
    Qs[tid >> 4][tid & 15] = ws[OFF_Q + (size_t)pair*D*D + tid];
    if (tid < 16) { float l = ls[a*D + tid]; ils2a[tid] = 1.0f/(l*l); }
    else if (tid < 32) { int d = tid - 16; float l = ls[b*D + d]; ils2b[d] = 1.0f/(l*l); }
    __syncthreads();
    for (int idx = tid; idx < 1024; idx += 256) {
        int r = idx >> 4, d = idx & 15;
        bufA[r][d] = ws[OFF_INP + (size_t)(n0 + r)*D + d] * ils2a[d];
    }
    __syncthreads();
    for (int idx = tid; idx < 1024; idx += 256) {
        int r = idx >> 4, j = idx & 15;
        float s = 0.f;
        #pragma unroll
        for (int i = 0; i < 16; ++i) s = fmaf(bufA[r][i], Qs[i][j], s);
        x1q[r][j] = s;
    }
    __syncthreads();
    if (tid < 64) {
        float xs1 = 0.f;
        #pragma unroll
        for (int j = 0; j < 16; ++j) xs1 = fmaf(x1q[tid][j], bufA[tid][j], xs1);
        u[tid]  = ws[OFF_KVEC + a*N + n0 + tid] + xs1;
        ba[tid] = ws[OFF_BETA + a*N + n0 + tid];
    }
    float sacc = 0.f, tacc = 0.f;
    for (int mt = 0; mt < 8; ++mt) {
        __syncthreads();
        for (int idx = tid; idx < 1024; idx += 256) {
            int r = idx >> 4, d = idx & 15;
            bufB[r][d] = ws[OFF_INP + (size_t)(mt*64 + r)*D + d] * ils2b[d];
        }
        __syncthreads();
        if (tid < 64) {
            float xs2 = 0.f;
            #pragma unroll
            for (int j = 0; j < 16; ++j) {
                float t2 = 0.f;
                #pragma unroll
                for (int i = 0; i < 16; ++i) t2 = fmaf(bufB[tid][i], Qs[i][j], t2);
                xs2 = fmaf(t2, bufB[tid][j], xs2);
            }
            v[tid]  = ws[OFF_KVEC + b*N + mt*64 + tid] + xs2;
            bb[tid] = ws[OFF_BETA + b*N + mt*64 + tid];
        }
        __syncthreads();
        float dacc[4][4] = {};
        #pragma unroll
        for (int d = 0; d < 16; ++d) {
            float av[4], bv[4];
            #pragma unroll
            for (int q = 0; q < 4; ++q) av[q] = x1q[ty*4+q][d];
            #pragma unroll
            for (int w = 0; w < 4; ++w) bv[w] = bufB[tx*4+w][d];
            #pragma unroll
            for (int q = 0; q < 4; ++q)
                #pragma unroll
                for (int w = 0; w < 4; ++w)
                    dacc[q][w] = fmaf(av[q], bv[w], dacc[q][w]);
        }
        #pragma unroll
        for (int q = 0; q < 4; ++q) {
            float uq = u[ty*4+q], baq = ba[ty*4+q];
            #pragma unroll
            for (int w = 0; w < 4; ++w) {
                float Lv = __expf(2.f*dacc[q][w] + uq + v[tx*4+w]);
                sacc = fmaf(baq * bb[tx*4+w], Lv, sacc);
                if (a == b) {
                    float ik = ws[OFF_A + ((size_t)a*N + n0 + ty*4 + q)*N + mt*64 + tx*4 + w];
                    tacc = fmaf(ik, Lv, tacc);
                }
            }
        }
    }
    red[tid] = sacc; __syncthreads();
    for (int o = 128; o > 0; o >>= 1) { if (tid < o) red[tid] += red[tid+o]; __syncthreads(); }
    if (tid == 0) ws[OFF_SPART + bid] = red[0];
    if (a == b) {
        __syncthreads();
        red[tid] = tacc; __syncthreads();
        for (int o = 128; o > 0; o >>= 1) { if (tid < o) red[tid] += red[tid+o]; __syncthreads(); }
        if (tid == 0) ws[OFF_TPART + a*8 + ntile] = red[0];
    }
}

// ---------- 8. finalize ----------
__global__ __launch_bounds__(256) void k_final(float* __restrict__ ws, const float* __restrict__ s,
                                               const float* __restrict__ os, float* __restrict__ out) {
    int tid = threadIdx.x;  // 256
    __shared__ float red[256];
    __shared__ float Msh[E], Vsh[E][D], cov[D][E+1];
    __shared__ float Sm[16][17], Si[16][17];

    for (int e = 0; e < E; ++e) {
        float p = 0.f;
        for (int n = tid; n < N; n += 256) p += ws[OFF_LB + e*N + n];
        red[tid] = p; __syncthreads();
        for (int o = 128; o > 0; o >>= 1) { if (tid < o) red[tid] += red[tid+o]; __syncthreads(); }
        if (tid == 0) Msh[e] = ws[OFF_C + e] * red[0];
        __syncthreads();
    }
    if (tid < E*D) {
        int e = tid / D, d = tid % D;
        float acc = 0.f;
        for (int n = 0; n < N; ++n)
            acc += ws[OFF_TIL + ((size_t)e*N + n)*D + d] * ws[OFF_LB + e*N + n];
        Vsh[e][d] = ws[OFF_C + e] * acc;
    }
    __syncthreads();

    if (tid < E*E) {
        int a = tid / E, bb = tid % E;
        float acc = 0.f;
        for (int q = 0; q < 8; ++q) acc += ws[OFF_SPART + (size_t)tid*8 + q];
        if (a == bb) {
            float tr = 0.f;
            for (int q = 0; q < 8; ++q) tr += ws[OFF_TPART + a*8 + q];
            acc -= tr;
        }
        acc *= ws[OFF_ISDR + tid];
        if (a == bb) acc += os[a];
        float v = acc - Msh[a]*Msh[bb];
        v *= ws[OFF_YSTD + a] * ws[OFF_YSTD + bb];
        out[E + tid] = v;                                // S
    }
    if (tid < E) out[tid] = Msh[tid]*ws[OFF_YSTD + tid] + ws[OFF_YMEAN + tid];  // Mout

    if (tid < D*E) {
        int d = tid / E, e = tid % E;
        float acc = 0.f;
        for (int k = 0; k < D; ++k) acc += ws[OFF_SSM + d*D + k] * Vsh[e][k];
        cov[d][e] = acc * ws[OFF_XSTD + d] * ws[OFF_YSTD + e];
    }
    int i = tid >> 4, j = tid & 15;
    Sm[i][j] = s[i*D + j];
    Si[i][j] = (i==j) ? 1.f : 0.f;
    __syncthreads();
    for (int k = 0; k < D; ++k) {
        float p   = Sm[k][k];
        float fik = Sm[i][k];
        float skj = Sm[k][j];
        float ikj = Si[k][j];
        __syncthreads();
        if (i == k) { Sm[k][j] = skj/p; Si[k][j] = ikj/p; }
        else        { float f = fik/p; Sm[i][j] -= f*skj; Si[i][j] -= f*ikj; }
        __syncthreads();
    }
    if (tid < D*E) {
        int d = tid / E, e = tid % E;
        float acc = 0.f;
        for (int k = 0; k < D; ++k) acc += Si[d][k] * cov[k][e];
        out[E + E*E + d*E + e] = acc;                    // Vout
    }
}

extern "C" void kernel_launch(void* const* d_in, const int* in_sizes, int n_in,
                              void* d_out, int out_size, void* d_ws, size_t ws_size,
                              hipStream_t stream) {
    const float* X     = (const float*)d_in[0];
    const float* Y     = (const float*)d_in[1];
    const float* m     = (const float*)d_in[2];
    const float* s     = (const float*)d_in[3];
    const float* ls    = (const float*)d_in[4];
    const float* os    = (const float*)d_in[5];
    const float* noise = (const float*)d_in[6];
    float* ws  = (float*)d_ws;
    float* out = (float*)d_out;

    k_prep   <<<1,    512, 0, stream>>>(X, Y, m, s, ws);
    k_buildA <<<E*64, 256, 0, stream>>>(ws, ls, os, noise);
    k_diag64 <<<E,    64,  0, stream>>>(ws, 0);
    for (int kk = 0; kk < 7; ++kk) {
        int k0 = kk*64;
        int nb = 7 - kk;
        k_panelmul<<<E*nb,            256, 0, stream>>>(ws, k0);
        k_traild  <<<E*nb*(nb+1)/2,   256, 0, stream>>>(ws, k0);
    }
    for (int d = 1; d < 8; ++d)
        k_tinv_off<<<E*(8-d), 256, 0, stream>>>(ws, d);
    k_syrk  <<<E*36,    256, 0, stream>>>(ws);
    k_beta  <<<E*4,     256, 0, stream>>>(ws);
    k_BR    <<<E+E*E,   256, 0, stream>>>(ws, ls, os);
    k_point <<<E*N/256, 256, 0, stream>>>(ws, ls, os);
    k_S     <<<E*E*8,   256, 0, stream>>>(ws, ls);
    k_final <<<1,       256, 0, stream>>>(ws, s, os, out);
}

// Round 7
// 857.720 us; speedup vs baseline: 2.4888x; 1.0947x over previous
//
#include <hip/hip_runtime.h>
#include <math.h>

constexpr int N = 512;
constexpr int D = 16;
constexpr int E = 12;

// ---- workspace layout (float offsets) ----
constexpr size_t OFF_A     = 0;                            // E*N*N  A -> L -> iK
constexpr size_t OFF_IK    = OFF_A    + (size_t)E*N*N;     // E*N*N  W = L^{-1}
constexpr size_t OFF_XS    = OFF_IK   + (size_t)E*N*N;     // N*D
constexpr size_t OFF_INP   = OFF_XS   + (size_t)N*D;       // N*D
constexpr size_t OFF_YN    = OFF_INP  + (size_t)N*D;       // E*N
constexpr size_t OFF_BETA  = OFF_YN   + (size_t)E*N;       // E*N
constexpr size_t OFF_KVEC  = OFF_BETA + (size_t)E*N;       // E*N
constexpr size_t OFF_LB    = OFF_KVEC + (size_t)E*N;       // E*N
constexpr size_t OFF_TIL   = OFF_LB   + (size_t)E*N;       // E*N*D
constexpr size_t OFF_U     = OFF_TIL  + (size_t)E*N*D;     // E*E*N  (kvec_a + xs1)
constexpr size_t OFF_V     = OFF_U    + (size_t)E*E*N;     // E*E*N  (kvec_b + xs2)
constexpr size_t OFF_Q     = OFF_V    + (size_t)E*E*N;     // E*E*D*D
constexpr size_t OFF_BINV  = OFF_Q    + (size_t)E*E*D*D;   // E*D*D
constexpr size_t OFF_C     = OFF_BINV + (size_t)E*D*D;     // E
constexpr size_t OFF_ISDR  = OFF_C    + E;                 // E*E
constexpr size_t OFF_SPART = OFF_ISDR + E*E;               // E*E*8
constexpr size_t OFF_TPART = OFF_SPART+ (size_t)E*E*8;     // E*8
constexpr size_t OFF_XMEAN = OFF_TPART+ (size_t)E*8;       // D
constexpr size_t OFF_XSTD  = OFF_XMEAN+ D;                 // D
constexpr size_t OFF_YMEAN = OFF_XSTD + D;                 // E
constexpr size_t OFF_YSTD  = OFF_YMEAN+ E;                 // E
constexpr size_t OFF_SSM   = OFF_YSTD + E;                 // D*D

// ---------- 1. standardization ----------
__global__ __launch_bounds__(512) void k_prep(const float* __restrict__ X, const float* __restrict__ Y,
                                              const float* __restrict__ m, const float* __restrict__ s,
                                              float* __restrict__ ws) {
    int tid = threadIdx.x;
    int lane = tid & 63, wave = tid >> 6;
    __shared__ float meanX[D], stdX[D], meanY[E], stdY[E], mmsh[D];

    for (int col = wave; col < D + E; col += 8) {
        float s1 = 0.f, s2 = 0.f;
        if (col < D) {
            #pragma unroll
            for (int i = 0; i < 8; ++i) { float v = X[(i*64 + lane)*D + col]; s1 += v; s2 += v*v; }
        } else {
            int e = col - D;
            #pragma unroll
            for (int i = 0; i < 8; ++i) { float v = Y[(i*64 + lane)*E + e]; s1 += v; s2 += v*v; }
        }
        #pragma unroll
        for (int off = 32; off > 0; off >>= 1) { s1 += __shfl_xor(s1, off); s2 += __shfl_xor(s2, off); }
        if (lane == 0) {
            float mean = s1 * (1.0f/N);
            float var  = (s2 - (float)N*mean*mean) * (1.0f/(N-1));
            float sd   = sqrtf(var);
            if (col < D) { meanX[col] = mean; stdX[col] = sd; }
            else         { meanY[col-D] = mean; stdY[col-D] = sd; }
        }
    }
    __syncthreads();
    if (tid < D) {
        mmsh[tid] = (m[tid] - meanX[tid]) / stdX[tid];
        ws[OFF_XMEAN + tid] = meanX[tid];
        ws[OFF_XSTD  + tid] = stdX[tid];
    }
    if (tid < E) { ws[OFF_YMEAN + tid] = meanY[tid]; ws[OFF_YSTD + tid] = stdY[tid]; }
    __syncthreads();
    int n = tid;
    #pragma unroll
    for (int d = 0; d < D; ++d) {
        float xs = (X[n*D + d] - meanX[d]) / stdX[d];
        ws[OFF_XS  + n*D + d] = xs;
        ws[OFF_INP + n*D + d] = xs - mmsh[d];
    }
    #pragma unroll
    for (int e = 0; e < E; ++e)
        ws[OFF_YN + e*N + n] = (Y[n*E + e] - meanY[e]) / stdY[e];
    if (tid < D*D) {
        int i = tid / D, j = tid % D;
        ws[OFF_SSM + tid] = s[tid] / (stdX[i] * stdX[j]);
    }
}

// ---------- 2. A = K + noise I (64x64 tiles)  +  appended B/R inverse blocks ----------
__global__ __launch_bounds__(256) void k_buildA(float* __restrict__ ws, const float* __restrict__ ls,
                                                const float* __restrict__ os, const float* __restrict__ noise) {
    int bid = blockIdx.x;
    int tid = threadIdx.x;
    if (bid < E*64) {
        int e  = bid >> 6;
        int t  = bid & 63;
        int bn = t >> 3, bm = t & 7;
        __shared__ float xn[64][17], xm[64][17];
        __shared__ float il2[16];
        for (int idx = tid; idx < 1024; idx += 256) {
            int r = idx >> 4, d0 = idx & 15;
            xn[r][d0] = ws[OFF_XS + (size_t)(bn*64 + r)*D + d0];
            xm[r][d0] = ws[OFF_XS + (size_t)(bm*64 + r)*D + d0];
        }
        if (tid < 16) { float l = ls[e*D + tid]; il2[tid] = 1.0f/(l*l); }
        __syncthreads();
        int tx = tid & 15, ty = tid >> 4;
        float osv = os[e], nsv = noise[e];
        float acc[4][4] = {};
        #pragma unroll
        for (int d = 0; d < 16; ++d) {
            float il = il2[d];
            float an[4], am[4];
            #pragma unroll
            for (int q = 0; q < 4; ++q) { an[q] = xn[ty + q*16][d]; am[q] = xm[tx + q*16][d]; }
            #pragma unroll
            for (int q = 0; q < 4; ++q)
                #pragma unroll
                for (int w = 0; w < 4; ++w) { float df = an[q] - am[w]; acc[q][w] = fmaf(df*df, il, acc[q][w]); }
        }
        float* A = ws + OFF_A + (size_t)e*N*N;
        #pragma unroll
        for (int q = 0; q < 4; ++q)
            #pragma unroll
            for (int w = 0; w < 4; ++w) {
                int nr = bn*64 + ty + q*16, mc = bm*64 + tx + w*16;
                float v = osv * __expf(-0.5f * acc[q][w]);
                if (nr == mc) v += nsv;
                A[(size_t)nr*N + mc] = v;
            }
        return;
    }
    // ---- BR part ----
    int bidx = bid - E*64;
    int i = tid >> 4, j = tid & 15;
    if (bidx < E) {
        int e = bidx;
        __shared__ float Bm[16][17], BInv[16][17];
        float li = ls[e*D + i], lj = ls[e*D + j];
        Bm[i][j] = ws[OFF_SSM + i*D + j] / (li*lj) + ((i==j) ? 1.f : 0.f);
        BInv[i][j] = (i==j) ? 1.f : 0.f;
        __syncthreads();
        float det = 1.f;
        for (int k = 0; k < D; ++k) {
            float p   = Bm[k][k];
            float fik = Bm[i][k];
            float bkj = Bm[k][j];
            float ikj = BInv[k][j];
            __syncthreads();
            det *= p;
            if (i == k) { Bm[k][j] = bkj/p; BInv[k][j] = ikj/p; }
            else        { float f = fik/p; Bm[i][j] -= f*bkj; BInv[i][j] -= f*ikj; }
            __syncthreads();
        }
        ws[OFF_BINV + ((size_t)e*D + i)*D + j] = BInv[i][j];
        if (tid == 0) ws[OFF_C + e] = os[e] / sqrtf(det);
    } else {
        int pair = bidx - E;
        int a = pair / E, b = pair % E;
        __shared__ float Rm[16][17], RInv[16][17], ssl[16][17];
        float la = ls[a*D + j], lb2 = ls[b*D + j];
        float rj = 1.f/(la*la) + 1.f/(lb2*lb2);
        float ssv = ws[OFF_SSM + i*D + j];
        ssl[i][j] = ssv;
        Rm[i][j] = ssv * rj + ((i==j) ? 1.f : 0.f);
        RInv[i][j] = (i==j) ? 1.f : 0.f;
        __syncthreads();
        float det = 1.f;
        for (int k = 0; k < D; ++k) {
            float p   = Rm[k][k];
            float fik = Rm[i][k];
            float rkj = Rm[k][j];
            float ikj = RInv[k][j];
            __syncthreads();
            det *= p;
            if (i == k) { Rm[k][j] = rkj/p; RInv[k][j] = ikj/p; }
            else        { float f = fik/p; Rm[i][j] -= f*rkj; RInv[i][j] -= f*ikj; }
            __syncthreads();
        }
        float q = 0.f;
        #pragma unroll
        for (int k2 = 0; k2 < D; ++k2) q += RInv[i][k2] * ssl[k2][j];
        ws[OFF_Q + ((size_t)pair*D + i)*D + j] = 0.5f * q;
        if (tid == 0) ws[OFF_ISDR + pair] = 1.f / sqrtf(det);
    }
}

// ---------- 3a. standalone 64x64 Cholesky + inverse for k0=0 (verified) ----------
__global__ __launch_bounds__(64) void k_diag64(float* __restrict__ ws, int k0) {
    int e = blockIdx.x;
    int lane = threadIdx.x;
    const float* A = ws + OFF_A + (size_t)e*N*N;
    float* W = ws + OFF_IK + (size_t)e*N*N;
    __shared__ float __align__(16) Lsh[64][68];
    __shared__ float colbuf[64];
    __shared__ float invdsh[64];

    float a[64];
    #pragma unroll
    for (int c = 0; c < 64; ++c) a[c] = A[(size_t)(k0 + c)*N + k0 + lane];

    #pragma unroll
    for (int k = 0; k < 64; ++k) {
        colbuf[lane] = a[k];
        __syncthreads();
        float dkk = colbuf[k];
        float dv = sqrtf(dkk), iv = 1.0f/dv;
        if (lane == k) { a[k] = dv; invdsh[k] = iv; }
        else if (lane > k) a[k] *= iv;
        colbuf[lane] = a[k];
        __syncthreads();
        float lrk = a[k];
        #pragma unroll
        for (int c = k + 1; c < 64; ++c)
            a[c] = fmaf(-lrk, colbuf[c], a[c]);
        __syncthreads();
    }
    #pragma unroll
    for (int c4 = 0; c4 < 16; ++c4) {
        float4 v; v.x = a[c4*4]; v.y = a[c4*4+1]; v.z = a[c4*4+2]; v.w = a[c4*4+3];
        *(float4*)&Lsh[lane][c4*4] = v;
    }
    float* Aw = ws + OFF_A + (size_t)e*N*N;
    #pragma unroll
    for (int c = 0; c < 64; ++c) Aw[(size_t)(k0 + lane)*N + k0 + c] = a[c];
    __syncthreads();

    float x[64];
    int c = lane;
    #pragma unroll
    for (int r = 0; r < 64; ++r) {
        float acc0 = (r == c) ? 1.0f : 0.0f, acc1 = 0.f, acc2 = 0.f, acc3 = 0.f;
        #pragma unroll
        for (int k4 = 0; k4 < (r >> 2); ++k4) {
            float4 L4 = *(const float4*)&Lsh[r][k4*4];
            acc0 = fmaf(-L4.x, x[k4*4+0], acc0);
            acc1 = fmaf(-L4.y, x[k4*4+1], acc1);
            acc2 = fmaf(-L4.z, x[k4*4+2], acc2);
            acc3 = fmaf(-L4.w, x[k4*4+3], acc3);
        }
        #pragma unroll
        for (int k = r & ~3; k < r; ++k)
            acc0 = fmaf(-Lsh[r][k], x[k], acc0);
        x[r] = ((acc0 + acc1) + (acc2 + acc3)) * invdsh[r];
    }
    #pragma unroll
    for (int r = 0; r < 64; ++r)
        W[(size_t)(k0 + r)*N + k0 + c] = x[r];
}

// ---------- 3b. panel TRSM as GEMM: P <- P * W_kk^T ----------
__global__ __launch_bounds__(256) void k_panelmul(float* __restrict__ ws, int k0) {
    int nb = (N - k0 - 64) >> 6;
    int e  = blockIdx.x / nb;
    int bi = blockIdx.x % nb;
    float* A = ws + OFF_A + (size_t)e*N*N;
    const float* W = ws + OFF_IK + (size_t)e*N*N;
    int r0 = k0 + 64 + bi*64;
    __shared__ float Ps[64][65], Wsh[64][65];
    int tid = threadIdx.x;
    for (int idx = tid; idx < 4096; idx += 256) {
        int r = idx >> 6, c2 = idx & 63;
        Ps[r][c2]  = A[(size_t)(r0 + r)*N + k0 + c2];
        Wsh[r][c2] = W[(size_t)(k0 + r)*N + k0 + c2];
    }
    __syncthreads();
    int tx = tid & 15, ty = tid >> 4;
    float acc[4][4] = {};
    #pragma unroll 8
    for (int j = 0; j < 64; ++j) {
        float pr[4], wr[4];
        #pragma unroll
        for (int q = 0; q < 4; ++q) { pr[q] = Ps[ty*4+q][j]; wr[q] = Wsh[tx*4+q][j]; }
        #pragma unroll
        for (int q = 0; q < 4; ++q)
            #pragma unroll
            for (int w = 0; w < 4; ++w) acc[q][w] = fmaf(pr[q], wr[w], acc[q][w]);
    }
    __syncthreads();
    #pragma unroll
    for (int q = 0; q < 4; ++q)
        #pragma unroll
        for (int w = 0; w < 4; ++w)
            A[(size_t)(r0 + ty*4 + q)*N + k0 + tx*4 + w] = acc[q][w];
}

// ---------- 3c. trailing SYRK + fused next-diag (verified) ----------
__global__ __launch_bounds__(256) void k_traild(float* __restrict__ ws, int k0) {
    int t0 = k0 + 64;
    int nb = (N - t0) >> 6;
    int ntiles = (nb*(nb+1)) >> 1;
    int e = blockIdx.x / ntiles;
    int t = blockIdx.x % ntiles;
    int bj = 0; while (t >= nb - bj) { t -= nb - bj; ++bj; }
    int bi = bj + t;
    bool isdiag = (bi == 0) && (bj == 0);
    float* A = ws + OFF_A + (size_t)e*N*N;
    const float* Pr = A + (size_t)(t0 + bi*64)*N + k0;
    const float* Pc = A + (size_t)(t0 + bj*64)*N + k0;
    __shared__ float Sr[64][65], Sc[64][65];
    __shared__ float __align__(16) Lsh[64][68];
    __shared__ float colbuf[64], invdsh[64];
    int tid = threadIdx.x;
    for (int idx = tid; idx < 4096; idx += 256) {
        int r = idx >> 6, c = idx & 63;
        Sr[r][c] = Pr[(size_t)r*N + c];
        Sc[r][c] = Pc[(size_t)r*N + c];
    }
    __syncthreads();
    int tx = tid & 15, ty = tid >> 4;
    float acc[4][4] = {};
    #pragma unroll 8
    for (int p = 0; p < 64; ++p) {
        float ar[4], ac[4];
        #pragma unroll
        for (int q = 0; q < 4; ++q) { ar[q] = Sr[ty*4+q][p]; ac[q] = Sc[tx*4+q][p]; }
        #pragma unroll
        for (int q = 0; q < 4; ++q)
            #pragma unroll
            for (int w = 0; w < 4; ++w) acc[q][w] = fmaf(ar[q], ac[w], acc[q][w]);
    }
    float* Out = A + (size_t)(t0 + bi*64)*N + (t0 + bj*64);
    if (!isdiag) {
        #pragma unroll
        for (int q = 0; q < 4; ++q)
            #pragma unroll
            for (int w = 0; w < 4; ++w)
                Out[(size_t)(ty*4+q)*N + tx*4+w] -= acc[q][w];
        return;
    }
    __syncthreads();
    #pragma unroll
    for (int q = 0; q < 4; ++q)
        #pragma unroll
        for (int w = 0; w < 4; ++w)
            Sr[ty*4+q][tx*4+w] = Out[(size_t)(ty*4+q)*N + tx*4+w] - acc[q][w];
    __syncthreads();

    bool act = tid < 64;
    int lane = tid;
    float a[64];
    if (act) {
        #pragma unroll
        for (int c = 0; c < 64; ++c) a[c] = Sr[c][lane];
    }
    #pragma unroll
    for (int k = 0; k < 64; ++k) {
        if (act && lane == k) {
            float dv = sqrtf(a[k]);
            a[k] = dv; colbuf[k] = dv; invdsh[k] = 1.0f/dv;
        }
        __syncthreads();
        if (act && lane > k) { a[k] *= invdsh[k]; colbuf[lane] = a[k]; }
        __syncthreads();
        if (act) {
            float lrk = a[k];
            #pragma unroll
            for (int c = k + 1; c < 64; ++c)
                a[c] = fmaf(-lrk, colbuf[c], a[c]);
        }
        __syncthreads();
    }
    if (act) {
        #pragma unroll
        for (int c4 = 0; c4 < 16; ++c4) {
            float4 v; v.x = a[c4*4]; v.y = a[c4*4+1]; v.z = a[c4*4+2]; v.w = a[c4*4+3];
            *(float4*)&Lsh[lane][c4*4] = v;
        }
        #pragma unroll
        for (int c = 0; c < 64; ++c)
            A[(size_t)(t0 + lane)*N + t0 + c] = a[c];
    }
    __syncthreads();
    if (act) {
        float* W = ws + OFF_IK + (size_t)e*N*N;
        float x[64];
        int c = lane;
        #pragma unroll
        for (int r = 0; r < 64; ++r) {
            float acc0 = (r == c) ? 1.0f : 0.0f, acc1 = 0.f, acc2 = 0.f, acc3 = 0.f;
            #pragma unroll
            for (int k4 = 0; k4 < (r >> 2); ++k4) {
                float4 L4 = *(const float4*)&Lsh[r][k4*4];
                acc0 = fmaf(-L4.x, x[k4*4+0], acc0);
                acc1 = fmaf(-L4.y, x[k4*4+1], acc1);
                acc2 = fmaf(-L4.z, x[k4*4+2], acc2);
                acc3 = fmaf(-L4.w, x[k4*4+3], acc3);
            }
            #pragma unroll
            for (int k = r & ~3; k < r; ++k)
                acc0 = fmaf(-Lsh[r][k], x[k], acc0);
            x[r] = ((acc0 + acc1) + (acc2 + acc3)) * invdsh[r];
        }
        #pragma unroll
        for (int r = 0; r < 64; ++r)
            W[(size_t)(t0 + r)*N + t0 + c] = x[r];
    }
}

// ---------- 3d. triangular inverse: one block per (e, column j), serial over i ----------
__global__ __launch_bounds__(512) void k_tinvcol(float* __restrict__ ws) {
    int e = blockIdx.x / 7;
    int j = blockIdx.x % 7;
    const float* L = ws + OFF_A  + (size_t)e*N*N;
    float*       W = ws + OFF_IK + (size_t)e*N*N;
    __shared__ float __align__(16) Sa[64][68];
    __shared__ float __align__(16) Sb[64][68];
    __shared__ float __align__(16) T [64][68];
    int tid = threadIdx.x;
    int tx = tid & 15, ty = tid >> 4;   // ty 0..31
    for (int i = j + 1; i < 8; ++i) {
        float acc[2][4] = {};
        for (int k = j; k < i; ++k) {
            __syncthreads();
            for (int idx = tid; idx < 4096; idx += 512) {
                int r = idx >> 6, c = idx & 63;
                Sa[r][c] = L[(size_t)(i*64+r)*N + k*64+c];
                Sb[r][c] = W[(size_t)(k*64+r)*N + j*64+c];
            }
            __syncthreads();
            #pragma unroll 8
            for (int p = 0; p < 64; ++p) {
                float a0 = Sa[ty*2][p], a1 = Sa[ty*2+1][p];
                float4 bv = *(const float4*)&Sb[p][tx*4];
                acc[0][0] = fmaf(a0, bv.x, acc[0][0]); acc[0][1] = fmaf(a0, bv.y, acc[0][1]);
                acc[0][2] = fmaf(a0, bv.z, acc[0][2]); acc[0][3] = fmaf(a0, bv.w, acc[0][3]);
                acc[1][0] = fmaf(a1, bv.x, acc[1][0]); acc[1][1] = fmaf(a1, bv.y, acc[1][1]);
                acc[1][2] = fmaf(a1, bv.z, acc[1][2]); acc[1][3] = fmaf(a1, bv.w, acc[1][3]);
            }
        }
        __syncthreads();
        { float4 v0; v0.x = acc[0][0]; v0.y = acc[0][1]; v0.z = acc[0][2]; v0.w = acc[0][3];
          float4 v1; v1.x = acc[1][0]; v1.y = acc[1][1]; v1.z = acc[1][2]; v1.w = acc[1][3];
          *(float4*)&T[ty*2][tx*4] = v0;
          *(float4*)&T[ty*2+1][tx*4] = v1; }
        for (int idx = tid; idx < 4096; idx += 512) {
            int r = idx >> 6, c = idx & 63;
            Sa[r][c] = W[(size_t)(i*64+r)*N + i*64+c];    // W_ii
        }
        __syncthreads();
        float o[2][4] = {};
        #pragma unroll 8
        for (int p = 0; p < 64; ++p) {
            float a0 = Sa[ty*2][p], a1 = Sa[ty*2+1][p];
            float4 bv = *(const float4*)&T[p][tx*4];
            o[0][0] = fmaf(a0, bv.x, o[0][0]); o[0][1] = fmaf(a0, bv.y, o[0][1]);
            o[0][2] = fmaf(a0, bv.z, o[0][2]); o[0][3] = fmaf(a0, bv.w, o[0][3]);
            o[1][0] = fmaf(a1, bv.x, o[1][0]); o[1][1] = fmaf(a1, bv.y, o[1][1]);
            o[1][2] = fmaf(a1, bv.z, o[1][2]); o[1][3] = fmaf(a1, bv.w, o[1][3]);
        }
        { float4 w0; w0.x = -o[0][0]; w0.y = -o[0][1]; w0.z = -o[0][2]; w0.w = -o[0][3];
          float4 w1; w1.x = -o[1][0]; w1.y = -o[1][1]; w1.z = -o[1][2]; w1.w = -o[1][3];
          *(float4*)&W[(size_t)(i*64 + ty*2)*N + j*64 + tx*4] = w0;
          *(float4*)&W[(size_t)(i*64 + ty*2 + 1)*N + j*64 + tx*4] = w1; }
        __syncthreads();
    }
}

// ---------- 3e. iK = W^T W  +  appended beta blocks (beta = W^T (W yn)) ----------
__global__ __launch_bounds__(256) void k_syrkbeta(float* __restrict__ ws) {
    int task = blockIdx.x;
    int tid = threadIdx.x;
    __shared__ float Sa[64][65], Sb[64][65];
    __shared__ float yn_s[N], z_s[N];
    __shared__ float zpart[64][5];
    if (task < E*36) {
        int e = task / 36;
        int t = task % 36;
        int bj = 0; while (t >= 8 - bj) { t -= 8 - bj; ++bj; }
        int bi = bj + t;
        const float* W = ws + OFF_IK + (size_t)e*N*N;
        float*      IK = ws + OFF_A  + (size_t)e*N*N;
        int tx = tid & 15, ty = tid >> 4;
        float acc[4][4] = {};
        for (int p = bi; p < 8; ++p) {
            __syncthreads();
            for (int idx = tid; idx < 4096; idx += 256) {
                int r = idx >> 6, cc = idx & 63;
                Sa[r][cc] = W[(size_t)(p*64+r)*N + bi*64+cc];
                Sb[r][cc] = W[(size_t)(p*64+r)*N + bj*64+cc];
            }
            __syncthreads();
            #pragma unroll 8
            for (int pr = 0; pr < 64; ++pr) {
                float ar[4], ac[4];
                #pragma unroll
                for (int q = 0; q < 4; ++q) { ar[q] = Sa[pr][ty*4+q]; ac[q] = Sb[pr][tx*4+q]; }
                #pragma unroll
                for (int q = 0; q < 4; ++q)
                    #pragma unroll
                    for (int w = 0; w < 4; ++w) acc[q][w] = fmaf(ar[q], ac[w], acc[q][w]);
            }
        }
        #pragma unroll
        for (int q = 0; q < 4; ++q)
            #pragma unroll
            for (int w = 0; w < 4; ++w) {
                int r = bi*64 + ty*4 + q, c = bj*64 + tx*4 + w;
                IK[(size_t)r*N + c] = acc[q][w];
                IK[(size_t)c*N + r] = acc[q][w];
            }
        return;
    }
    // ---- beta from W ----
    int e = task - E*36;
    const float* W = ws + OFF_IK + (size_t)e*N*N;
    for (int i = tid; i < N; i += 256) yn_s[i] = ws[OFF_YN + (size_t)e*N + i];
    __syncthreads();
    // z = W yn (lower block-triangular), tiled
    int r = tid & 63, g = tid >> 6;   // 4 col-groups of 16
    for (int rb = 0; rb < 8; ++rb) {
        float part = 0.f;
        for (int cb = 0; cb <= rb; ++cb) {
            __syncthreads();
            for (int idx = tid; idx < 4096; idx += 256) {
                int rr = idx >> 6, cc = idx & 63;
                Sa[rr][cc] = W[(size_t)(rb*64+rr)*N + cb*64+cc];
            }
            __syncthreads();
            #pragma unroll
            for (int c0 = 0; c0 < 16; ++c0) {
                int c = g*16 + c0;
                part = fmaf(Sa[r][c], yn_s[cb*64 + c], part);
            }
        }
        zpart[r][g] = part;
        __syncthreads();
        if (tid < 64)
            z_s[rb*64 + tid] = (zpart[tid][0] + zpart[tid][1]) + (zpart[tid][2] + zpart[tid][3]);
        __syncthreads();
    }
    // beta = W^T z  (coalesced column reads)
    for (int c = tid; c < N; c += 256) {
        int r0 = c & ~63;
        float a0 = 0.f, a1 = 0.f;
        for (int rr = r0; rr < N; rr += 2) {
            a0 = fmaf(W[(size_t)rr*N + c],     z_s[rr],   a0);
            a1 = fmaf(W[(size_t)(rr+1)*N + c], z_s[rr+1], a1);
        }
        ws[OFF_BETA + e*N + c] = a0 + a1;
    }
}

// ---------- 5. per (e,n): iN, t, lb, tiL, kvec ----------
__global__ __launch_bounds__(256) void k_point(float* __restrict__ ws, const float* __restrict__ ls,
                                               const float* __restrict__ os) {
    int t = blockIdx.x*256 + threadIdx.x;
    int e = t >> 9, n = t & 511;
    float iN[D], tt[D], l[D];
    #pragma unroll
    for (int d = 0; d < D; ++d) { l[d] = ls[e*D + d]; iN[d] = ws[OFF_INP + n*D + d] / l[d]; }
    #pragma unroll
    for (int d = 0; d < D; ++d) {
        float acc = 0.f;
        #pragma unroll
        for (int j = 0; j < D; ++j) acc += ws[OFF_BINV + ((size_t)e*D + d)*D + j] * iN[j];
        tt[d] = acc;
    }
    float siNt = 0.f, siN2 = 0.f;
    #pragma unroll
    for (int d = 0; d < D; ++d) { siNt += iN[d]*tt[d]; siN2 += iN[d]*iN[d]; }
    float lbv = __expf(-0.5f * siNt) * ws[OFF_BETA + e*N + n];
    ws[OFF_LB + e*N + n] = lbv;
    #pragma unroll
    for (int d = 0; d < D; ++d) ws[OFF_TIL + ((size_t)e*N + n)*D + d] = tt[d] / l[d];
    ws[OFF_KVEC + e*N + n] = logf(os[e]) - 0.5f * siN2;
}

// ---------- 6. U/V = kvec + quadratic forms per (pair, n) ----------
__global__ __launch_bounds__(256) void k_xs(float* __restrict__ ws, const float* __restrict__ ls) {
    int t = blockIdx.x*256 + threadIdx.x;   // E*E*N
    int pair = t / N, n = t % N;
    int a = pair / E, b = pair % E;
    int tid = threadIdx.x;
    __shared__ float Qs[16][17];
    __shared__ float i2a[16], i2b[16];
    Qs[tid >> 4][tid & 15] = ws[OFF_Q + (size_t)pair*D*D + tid];
    if (tid < 16) { float l = ls[a*D + tid]; i2a[tid] = 1.0f/(l*l); }
    else if (tid < 32) { int d = tid-16; float l = ls[b*D + d]; i2b[d] = 1.0f/(l*l); }
    __syncthreads();
    float x1[D], x2[D];
    #pragma unroll
    for (int d = 0; d < D; ++d) {
        float ip = ws[OFF_INP + n*D + d];
        x1[d] = ip * i2a[d];
        x2[d] = ip * i2b[d];
    }
    float xs1 = 0.f, xs2 = 0.f;
    #pragma unroll
    for (int j = 0; j < D; ++j) {
        float t1 = 0.f, t2 = 0.f;
        #pragma unroll
        for (int i = 0; i < D; ++i) { t1 = fmaf(x1[i], Qs[i][j], t1); t2 = fmaf(x2[i], Qs[i][j], t2); }
        xs1 = fmaf(t1, x1[j], xs1);
        xs2 = fmaf(t2, x2[j], xs2);
    }
    ws[OFF_U + (size_t)pair*N + n] = ws[OFF_KVEC + a*N + n] + xs1;
    ws[OFF_V + (size_t)pair*N + n] = ws[OFF_KVEC + b*N + n] + xs2;
}

// ---------- 7. big cross-term: d-major LDS, reg-cached A-side, b128 B-side ----------
__global__ __launch_bounds__(256) void k_S(float* __restrict__ ws, const float* __restrict__ ls) {
    int bid = blockIdx.x;            // E*E*8
    int pair = bid >> 3, ntile = bid & 7;
    int a = pair / E, b = pair % E;
    int tid = threadIdx.x;
    int tx = tid & 15, ty = tid >> 4;
    __shared__ float Qs[16][17];
    __shared__ float i2a[16], i2b[16];
    __shared__ float __align__(16) bufAT[16][68];
    __shared__ float __align__(16) x1qT[16][68];
    __shared__ float __align__(16) bufBT[16][68];
    __shared__ float u_s[64], v_s[64], ba_s[64], bb_s[64];
    __shared__ float red[256];
    int n0 = ntile*64;
    Qs[tid >> 4][tid & 15] = ws[OFF_Q + (size_t)pair*D*D + tid];
    if (tid < 16) { float l = ls[a*D + tid]; i2a[tid] = 1.0f/(l*l); }
    else if (tid < 32) { int d = tid-16; float l = ls[b*D + d]; i2b[d] = 1.0f/(l*l); }
    __syncthreads();
    for (int idx = tid; idx < 1024; idx += 256) {
        int r = idx >> 4, d = idx & 15;
        bufAT[d][r] = ws[OFF_INP + (size_t)(n0 + r)*D + d] * i2a[d];
    }
    __syncthreads();
    for (int idx = tid; idx < 1024; idx += 256) {
        int r = idx >> 4, j = idx & 15;
        float s = 0.f;
        #pragma unroll
        for (int i = 0; i < 16; ++i) s = fmaf(bufAT[i][r], Qs[i][j], s);
        x1qT[j][r] = s;
    }
    if (tid < 64) {
        u_s[tid]  = ws[OFF_U + (size_t)pair*N + n0 + tid];
        ba_s[tid] = ws[OFF_BETA + a*N + n0 + tid];
    }
    __syncthreads();
    // register-cache A side
    float4 av4[16];
    #pragma unroll
    for (int d = 0; d < 16; ++d) av4[d] = *(const float4*)&x1qT[d][ty*4];
    float uq[4], baq[4];
    #pragma unroll
    for (int q = 0; q < 4; ++q) { uq[q] = u_s[ty*4+q]; baq[q] = ba_s[ty*4+q]; }

    float sacc = 0.f, tacc = 0.f;
    for (int mt = 0; mt < 8; ++mt) {
        __syncthreads();
        for (int idx = tid; idx < 1024; idx += 256) {
            int r = idx >> 4, d = idx & 15;
            bufBT[d][r] = ws[OFF_INP + (size_t)(mt*64 + r)*D + d] * i2b[d];
        }
        if (tid < 64) {
            v_s[tid]  = ws[OFF_V + (size_t)pair*N + mt*64 + tid];
            bb_s[tid] = ws[OFF_BETA + b*N + mt*64 + tid];
        }
        __syncthreads();
        float dacc[4][4] = {};
        #pragma unroll
        for (int d = 0; d < 16; ++d) {
            float4 bv = *(const float4*)&bufBT[d][tx*4];
            float4 av = av4[d];
            dacc[0][0] = fmaf(av.x, bv.x, dacc[0][0]); dacc[0][1] = fmaf(av.x, bv.y, dacc[0][1]);
            dacc[0][2] = fmaf(av.x, bv.z, dacc[0][2]); dacc[0][3] = fmaf(av.x, bv.w, dacc[0][3]);
            dacc[1][0] = fmaf(av.y, bv.x, dacc[1][0]); dacc[1][1] = fmaf(av.y, bv.y, dacc[1][1]);
            dacc[1][2] = fmaf(av.y, bv.z, dacc[1][2]); dacc[1][3] = fmaf(av.y, bv.w, dacc[1][3]);
            dacc[2][0] = fmaf(av.z, bv.x, dacc[2][0]); dacc[2][1] = fmaf(av.z, bv.y, dacc[2][1]);
            dacc[2][2] = fmaf(av.z, bv.z, dacc[2][2]); dacc[2][3] = fmaf(av.z, bv.w, dacc[2][3]);
            dacc[3][0] = fmaf(av.w, bv.x, dacc[3][0]); dacc[3][1] = fmaf(av.w, bv.y, dacc[3][1]);
            dacc[3][2] = fmaf(av.w, bv.z, dacc[3][2]); dacc[3][3] = fmaf(av.w, bv.w, dacc[3][3]);
        }
        #pragma unroll
        for (int q = 0; q < 4; ++q) {
            #pragma unroll
            for (int w = 0; w < 4; ++w) {
                float Lv = __expf(2.f*dacc[q][w] + uq[q] + v_s[tx*4+w]);
                sacc = fmaf(baq[q] * bb_s[tx*4+w], Lv, sacc);
                if (a == b) {
                    float ik = ws[OFF_A + ((size_t)a*N + n0 + ty*4 + q)*N + mt*64 + tx*4 + w];
                    tacc = fmaf(ik, Lv, tacc);
                }
            }
        }
    }
    red[tid] = sacc; __syncthreads();
    for (int o = 128; o > 0; o >>= 1) { if (tid < o) red[tid] += red[tid+o]; __syncthreads(); }
    if (tid == 0) ws[OFF_SPART + bid] = red[0];
    if (a == b) {
        __syncthreads();
        red[tid] = tacc; __syncthreads();
        for (int o = 128; o > 0; o >>= 1) { if (tid < o) red[tid] += red[tid+o]; __syncthreads(); }
        if (tid == 0) ws[OFF_TPART + a*8 + ntile] = red[0];
    }
}

// ---------- 8. finalize ----------
__global__ __launch_bounds__(256) void k_final(float* __restrict__ ws, const float* __restrict__ s,
                                               const float* __restrict__ os, float* __restrict__ out) {
    int tid = threadIdx.x;
    __shared__ float Msh[E], Vsh[E][D], cov[D][E+1];
    __shared__ float Sm[16][17], Si[16][17];
    __shared__ float vred[16][17];

    // M: wave-shuffle reductions
    {
        int wv = tid >> 6, lane = tid & 63;
        for (int e = wv; e < E; e += 4) {
            float sum = 0.f;
            #pragma unroll
            for (int i = 0; i < 8; ++i) sum += ws[OFF_LB + e*N + i*64 + lane];
            #pragma unroll
            for (int off = 32; off > 0; off >>= 1) sum += __shfl_xor(sum, off);
            if (lane == 0) Msh[e] = ws[OFF_C + e] * sum;
        }
    }
    // V: tiled coalesced reduction
    for (int e = 0; e < E; ++e) {
        int d = tid & 15, sl = tid >> 4;
        float acc = 0.f;
        for (int i = 0; i < 32; ++i) {
            int n = sl*32 + i;
            acc = fmaf(ws[OFF_TIL + ((size_t)e*N + n)*D + d], ws[OFF_LB + e*N + n], acc);
        }
        vred[sl][d] = acc;
        __syncthreads();
        if (tid < 16) {
            float sum = 0.f;
            #pragma unroll
            for (int s2 = 0; s2 < 16; ++s2) sum += vred[s2][tid];
            Vsh[e][tid] = ws[OFF_C + e] * sum;
        }
        __syncthreads();
    }

    if (tid < E*E) {
        int a = tid / E, bb = tid % E;
        float acc = 0.f;
        for (int q = 0; q < 8; ++q) acc += ws[OFF_SPART + (size_t)tid*8 + q];
        if (a == bb) {
            float tr = 0.f;
            for (int q = 0; q < 8; ++q) tr += ws[OFF_TPART + a*8 + q];
            acc -= tr;
        }
        acc *= ws[OFF_ISDR + tid];
        if (a == bb) acc += os[a];
        float v = acc - Msh[a]*Msh[bb];
        v *= ws[OFF_YSTD + a] * ws[OFF_YSTD + bb];
        out[E + tid] = v;                                // S
    }
    if (tid < E) out[tid] = Msh[tid]*ws[OFF_YSTD + tid] + ws[OFF_YMEAN + tid];  // Mout

    if (tid < D*E) {
        int d = tid / E, e = tid % E;
        float acc = 0.f;
        for (int k = 0; k < D; ++k) acc += ws[OFF_SSM + d*D + k] * Vsh[e][k];
        cov[d][e] = acc * ws[OFF_XSTD + d] * ws[OFF_YSTD + e];
    }
    int i = tid >> 4, j = tid & 15;
    Sm[i][j] = s[i*D + j];
    Si[i][j] = (i==j) ? 1.f : 0.f;
    __syncthreads();
    for (int k = 0; k < D; ++k) {
        float p   = Sm[k][k];
        float fik = Sm[i][k];
        float skj = Sm[k][j];
        float ikj = Si[k][j];
        __syncthreads();
        if (i == k) { Sm[k][j] = skj/p; Si[k][j] = ikj/p; }
        else        { float f = fik/p; Sm[i][j] -= f*skj; Si[i][j] -= f*ikj; }
        __syncthreads();
    }
    if (tid < D*E) {
        int d = tid / E, e = tid % E;
        float acc = 0.f;
        for (int k = 0; k < D; ++k) acc += Si[d][k] * cov[k][e];
        out[E + E*E + d*E + e] = acc;                    // Vout
    }
}

extern "C" void kernel_launch(void* const* d_in, const int* in_sizes, int n_in,
                              void* d_out, int out_size, void* d_ws, size_t ws_size,
                              hipStream_t stream) {
    const float* X     = (const float*)d_in[0];
    const float* Y     = (const float*)d_in[1];
    const float* m     = (const float*)d_in[2];
    const float* s     = (const float*)d_in[3];
    const float* ls    = (const float*)d_in[4];
    const float* os    = (const float*)d_in[5];
    const float* noise = (const float*)d_in[6];
    float* ws  = (float*)d_ws;
    float* out = (float*)d_out;

    k_prep   <<<1,              512, 0, stream>>>(X, Y, m, s, ws);
    k_buildA <<<E*64 + E + E*E, 256, 0, stream>>>(ws, ls, os, noise);
    k_diag64 <<<E,              64,  0, stream>>>(ws, 0);
    for (int kk = 0; kk < 7; ++kk) {
        int k0 = kk*64;
        int nb = 7 - kk;
        k_panelmul<<<E*nb,          256, 0, stream>>>(ws, k0);
        k_traild  <<<E*nb*(nb+1)/2, 256, 0, stream>>>(ws, k0);
    }
    k_tinvcol <<<E*7,        512, 0, stream>>>(ws);
    k_syrkbeta<<<E*36 + E,   256, 0, stream>>>(ws);
    k_point   <<<E*N/256,    256, 0, stream>>>(ws, ls, os);
    k_xs      <<<E*E*N/256,  256, 0, stream>>>(ws, ls);
    k_S       <<<E*E*8,      256, 0, stream>>>(ws, ls);
    k_final   <<<1,          256, 0, stream>>>(ws, s, os, out);
}

// Round 8
// 764.454 us; speedup vs baseline: 2.7925x; 1.1220x over previous
//
#include <hip/hip_runtime.h>
#include <math.h>

constexpr int N = 512;
constexpr int D = 16;
constexpr int E = 12;

// ---- workspace layout (float offsets) ----
constexpr size_t OFF_A     = 0;                            // E*N*N  A -> trail -> iK
constexpr size_t OFF_IK    = OFF_A    + (size_t)E*N*N;     // E*N*N  W = L^{-1}
constexpr size_t OFF_XS    = OFF_IK   + (size_t)E*N*N;     // N*D
constexpr size_t OFF_INP   = OFF_XS   + (size_t)N*D;       // N*D
constexpr size_t OFF_YN    = OFF_INP  + (size_t)N*D;       // E*N
constexpr size_t OFF_BETA  = OFF_YN   + (size_t)E*N;       // E*N
constexpr size_t OFF_KVEC  = OFF_BETA + (size_t)E*N;       // E*N
constexpr size_t OFF_LB    = OFF_KVEC + (size_t)E*N;       // E*N
constexpr size_t OFF_TIL   = OFF_LB   + (size_t)E*N;       // E*N*D
constexpr size_t OFF_U     = OFF_TIL  + (size_t)E*N*D;     // E*E*N
constexpr size_t OFF_V     = OFF_U    + (size_t)E*E*N;     // E*E*N
constexpr size_t OFF_Q     = OFF_V    + (size_t)E*E*N;     // E*E*D*D
constexpr size_t OFF_BINV  = OFF_Q    + (size_t)E*E*D*D;   // E*D*D
constexpr size_t OFF_C     = OFF_BINV + (size_t)E*D*D;     // E
constexpr size_t OFF_ISDR  = OFF_C    + E;                 // E*E
constexpr size_t OFF_SPART = OFF_ISDR + E*E;               // E*E*8
constexpr size_t OFF_TPART = OFF_SPART+ (size_t)E*E*8;     // E*8
constexpr size_t OFF_XMEAN = OFF_TPART+ (size_t)E*8;       // D
constexpr size_t OFF_XSTD  = OFF_XMEAN+ D;                 // D
constexpr size_t OFF_YMEAN = OFF_XSTD + D;                 // E
constexpr size_t OFF_YSTD  = OFF_YMEAN+ E;                 // E
constexpr size_t OFF_SSM   = OFF_YSTD + E;                 // D*D
constexpr size_t OFF_P     = OFF_SSM  + D*D;               // E*1792*64  (L panels, compact)

__device__ __forceinline__ int prow(int k) { return k*(480 - 32*k); }  // row offset of panel k

// ---------- 1. standardization ----------
__global__ __launch_bounds__(512) void k_prep(const float* __restrict__ X, const float* __restrict__ Y,
                                              const float* __restrict__ m, const float* __restrict__ s,
                                              float* __restrict__ ws) {
    int tid = threadIdx.x;
    int lane = tid & 63, wave = tid >> 6;
    __shared__ float meanX[D], stdX[D], meanY[E], stdY[E], mmsh[D];

    for (int col = wave; col < D + E; col += 8) {
        float s1 = 0.f, s2 = 0.f;
        if (col < D) {
            #pragma unroll
            for (int i = 0; i < 8; ++i) { float v = X[(i*64 + lane)*D + col]; s1 += v; s2 += v*v; }
        } else {
            int e = col - D;
            #pragma unroll
            for (int i = 0; i < 8; ++i) { float v = Y[(i*64 + lane)*E + e]; s1 += v; s2 += v*v; }
        }
        #pragma unroll
        for (int off = 32; off > 0; off >>= 1) { s1 += __shfl_xor(s1, off); s2 += __shfl_xor(s2, off); }
        if (lane == 0) {
            float mean = s1 * (1.0f/N);
            float var  = (s2 - (float)N*mean*mean) * (1.0f/(N-1));
            float sd   = sqrtf(var);
            if (col < D) { meanX[col] = mean; stdX[col] = sd; }
            else         { meanY[col-D] = mean; stdY[col-D] = sd; }
        }
    }
    __syncthreads();
    if (tid < D) {
        mmsh[tid] = (m[tid] - meanX[tid]) / stdX[tid];
        ws[OFF_XMEAN + tid] = meanX[tid];
        ws[OFF_XSTD  + tid] = stdX[tid];
    }
    if (tid < E) { ws[OFF_YMEAN + tid] = meanY[tid]; ws[OFF_YSTD + tid] = stdY[tid]; }
    __syncthreads();
    int n = tid;
    #pragma unroll
    for (int d = 0; d < D; ++d) {
        float xs = (X[n*D + d] - meanX[d]) / stdX[d];
        ws[OFF_XS  + n*D + d] = xs;
        ws[OFF_INP + n*D + d] = xs - mmsh[d];
    }
    #pragma unroll
    for (int e = 0; e < E; ++e)
        ws[OFF_YN + e*N + n] = (Y[n*E + e] - meanY[e]) / stdY[e];
    if (tid < D*D) {
        int i = tid / D, j = tid % D;
        ws[OFF_SSM + tid] = s[tid] / (stdX[i] * stdX[j]);
    }
}

// ---------- 2. A = K + noise I  +  appended B/R inverse blocks ----------
__global__ __launch_bounds__(256) void k_buildA(float* __restrict__ ws, const float* __restrict__ ls,
                                                const float* __restrict__ os, const float* __restrict__ noise) {
    int bid = blockIdx.x;
    int tid = threadIdx.x;
    if (bid < E*64) {
        int e  = bid >> 6;
        int t  = bid & 63;
        int bn = t >> 3, bm = t & 7;
        __shared__ float xn[64][17], xm[64][17];
        __shared__ float il2[16];
        for (int idx = tid; idx < 1024; idx += 256) {
            int r = idx >> 4, d0 = idx & 15;
            xn[r][d0] = ws[OFF_XS + (size_t)(bn*64 + r)*D + d0];
            xm[r][d0] = ws[OFF_XS + (size_t)(bm*64 + r)*D + d0];
        }
        if (tid < 16) { float l = ls[e*D + tid]; il2[tid] = 1.0f/(l*l); }
        __syncthreads();
        int tx = tid & 15, ty = tid >> 4;
        float osv = os[e], nsv = noise[e];
        float acc[4][4] = {};
        #pragma unroll
        for (int d = 0; d < 16; ++d) {
            float il = il2[d];
            float an[4], am[4];
            #pragma unroll
            for (int q = 0; q < 4; ++q) { an[q] = xn[ty + q*16][d]; am[q] = xm[tx + q*16][d]; }
            #pragma unroll
            for (int q = 0; q < 4; ++q)
                #pragma unroll
                for (int w = 0; w < 4; ++w) { float df = an[q] - am[w]; acc[q][w] = fmaf(df*df, il, acc[q][w]); }
        }
        float* A = ws + OFF_A + (size_t)e*N*N;
        #pragma unroll
        for (int q = 0; q < 4; ++q)
            #pragma unroll
            for (int w = 0; w < 4; ++w) {
                int nr = bn*64 + ty + q*16, mc = bm*64 + tx + w*16;
                float v = osv * __expf(-0.5f * acc[q][w]);
                if (nr == mc) v += nsv;
                A[(size_t)nr*N + mc] = v;
            }
        return;
    }
    int bidx = bid - E*64;
    int i = tid >> 4, j = tid & 15;
    if (bidx < E) {
        int e = bidx;
        __shared__ float Bm[16][17], BInv[16][17];
        float li = ls[e*D + i], lj = ls[e*D + j];
        Bm[i][j] = ws[OFF_SSM + i*D + j] / (li*lj) + ((i==j) ? 1.f : 0.f);
        BInv[i][j] = (i==j) ? 1.f : 0.f;
        __syncthreads();
        float det = 1.f;
        for (int k = 0; k < D; ++k) {
            float p   = Bm[k][k];
            float fik = Bm[i][k];
            float bkj = Bm[k][j];
            float ikj = BInv[k][j];
            __syncthreads();
            det *= p;
            if (i == k) { Bm[k][j] = bkj/p; BInv[k][j] = ikj/p; }
            else        { float f = fik/p; Bm[i][j] -= f*bkj; BInv[i][j] -= f*ikj; }
            __syncthreads();
        }
        ws[OFF_BINV + ((size_t)e*D + i)*D + j] = BInv[i][j];
        if (tid == 0) ws[OFF_C + e] = os[e] / sqrtf(det);
    } else {
        int pair = bidx - E;
        int a = pair / E, b = pair % E;
        __shared__ float Rm[16][17], RInv[16][17], ssl[16][17];
        float la = ls[a*D + j], lb2 = ls[b*D + j];
        float rj = 1.f/(la*la) + 1.f/(lb2*lb2);
        float ssv = ws[OFF_SSM + i*D + j];
        ssl[i][j] = ssv;
        Rm[i][j] = ssv * rj + ((i==j) ? 1.f : 0.f);
        RInv[i][j] = (i==j) ? 1.f : 0.f;
        __syncthreads();
        float det = 1.f;
        for (int k = 0; k < D; ++k) {
            float p   = Rm[k][k];
            float fik = Rm[i][k];
            float rkj = Rm[k][j];
            float ikj = RInv[k][j];
            __syncthreads();
            det *= p;
            if (i == k) { Rm[k][j] = rkj/p; RInv[k][j] = ikj/p; }
            else        { float f = fik/p; Rm[i][j] -= f*rkj; RInv[i][j] -= f*ikj; }
            __syncthreads();
        }
        float q = 0.f;
        #pragma unroll
        for (int k2 = 0; k2 < D; ++k2) q += RInv[i][k2] * ssl[k2][j];
        ws[OFF_Q + ((size_t)pair*D + i)*D + j] = 0.5f * q;
        if (tid == 0) ws[OFF_ISDR + pair] = 1.f / sqrtf(det);
    }
}

// ---------- 3a. standalone 64x64 Cholesky + inverse for k0=0 (verified) ----------
__global__ __launch_bounds__(64) void k_diag64(float* __restrict__ ws, int k0) {
    int e = blockIdx.x;
    int lane = threadIdx.x;
    const float* A = ws + OFF_A + (size_t)e*N*N;
    float* W = ws + OFF_IK + (size_t)e*N*N;
    __shared__ float __align__(16) Lsh[64][68];
    __shared__ float colbuf[64];
    __shared__ float invdsh[64];

    float a[64];
    #pragma unroll
    for (int c = 0; c < 64; ++c) a[c] = A[(size_t)(k0 + c)*N + k0 + lane];

    #pragma unroll
    for (int k = 0; k < 64; ++k) {
        colbuf[lane] = a[k];
        __syncthreads();
        float dkk = colbuf[k];
        float dv = sqrtf(dkk), iv = 1.0f/dv;
        if (lane == k) { a[k] = dv; invdsh[k] = iv; }
        else if (lane > k) a[k] *= iv;
        colbuf[lane] = a[k];
        __syncthreads();
        float lrk = a[k];
        #pragma unroll
        for (int c = k + 1; c < 64; ++c)
            a[c] = fmaf(-lrk, colbuf[c], a[c]);
        __syncthreads();
    }
    #pragma unroll
    for (int c4 = 0; c4 < 16; ++c4) {
        float4 v; v.x = a[c4*4]; v.y = a[c4*4+1]; v.z = a[c4*4+2]; v.w = a[c4*4+3];
        *(float4*)&Lsh[lane][c4*4] = v;
    }
    __syncthreads();

    float x[64];
    int c = lane;
    #pragma unroll
    for (int r = 0; r < 64; ++r) {
        float acc0 = (r == c) ? 1.0f : 0.0f, acc1 = 0.f, acc2 = 0.f, acc3 = 0.f;
        #pragma unroll
        for (int k4 = 0; k4 < (r >> 2); ++k4) {
            float4 L4 = *(const float4*)&Lsh[r][k4*4];
            acc0 = fmaf(-L4.x, x[k4*4+0], acc0);
            acc1 = fmaf(-L4.y, x[k4*4+1], acc1);
            acc2 = fmaf(-L4.z, x[k4*4+2], acc2);
            acc3 = fmaf(-L4.w, x[k4*4+3], acc3);
        }
        #pragma unroll
        for (int k = r & ~3; k < r; ++k)
            acc0 = fmaf(-Lsh[r][k], x[k], acc0);
        x[r] = ((acc0 + acc1) + (acc2 + acc3)) * invdsh[r];
    }
    #pragma unroll
    for (int r = 0; r < 64; ++r)
        W[(size_t)(k0 + r)*N + k0 + c] = x[r];
}

// ---------- 3b. trailing update: panel recompute (P=A_raw W^T) + SYRK + fused next diag ----------
__global__ __launch_bounds__(256) void k_traild(float* __restrict__ ws, int k0) {
    int kk = k0 >> 6;
    int t0 = k0 + 64;
    int nb = (N - t0) >> 6;
    int ntiles = (nb*(nb+1)) >> 1;
    int e = blockIdx.x / ntiles;
    int t = blockIdx.x % ntiles;
    int bj = 0; while (t >= nb - bj) { t -= nb - bj; ++bj; }
    int bi = bj + t;
    bool same = (bi == bj);
    bool isdiag0 = (bi == 0) && (bj == 0);
    float* A = ws + OFF_A + (size_t)e*N*N;
    const float* Wd = ws + OFF_IK + (size_t)e*N*N;
    __shared__ float Wsh[64][65], Sr[64][65], Sc[64][65];
    __shared__ float colbuf[64], invdsh[64];
    int tid = threadIdx.x;
    int tx = tid & 15, ty = tid >> 4;

    for (int idx = tid; idx < 4096; idx += 256) {
        int r = idx >> 6, c = idx & 63;
        Wsh[r][c] = Wd[(size_t)(k0 + r)*N + k0 + c];
        Sr[r][c]  = A[(size_t)(t0 + bi*64 + r)*N + k0 + c];
        if (!same) Sc[r][c] = A[(size_t)(t0 + bj*64 + r)*N + k0 + c];
    }
    __syncthreads();
    // panel TRSM via GEMM with W_kk = L_kk^{-1}
    float pr[4][4] = {}, pc[4][4] = {};
    if (same) {
        #pragma unroll 8
        for (int j = 0; j < 64; ++j) {
            float w4[4], a4[4];
            #pragma unroll
            for (int q = 0; q < 4; ++q) { w4[q] = Wsh[tx*4+q][j]; a4[q] = Sr[ty*4+q][j]; }
            #pragma unroll
            for (int q = 0; q < 4; ++q)
                #pragma unroll
                for (int w = 0; w < 4; ++w) pr[q][w] = fmaf(a4[q], w4[w], pr[q][w]);
        }
    } else {
        #pragma unroll 4
        for (int j = 0; j < 64; ++j) {
            float w4[4], a4[4], c4[4];
            #pragma unroll
            for (int q = 0; q < 4; ++q) { w4[q] = Wsh[tx*4+q][j]; a4[q] = Sr[ty*4+q][j]; c4[q] = Sc[ty*4+q][j]; }
            #pragma unroll
            for (int q = 0; q < 4; ++q)
                #pragma unroll
                for (int w = 0; w < 4; ++w) {
                    pr[q][w] = fmaf(a4[q], w4[w], pr[q][w]);
                    pc[q][w] = fmaf(c4[q], w4[w], pc[q][w]);
                }
        }
    }
    __syncthreads();
    #pragma unroll
    for (int q = 0; q < 4; ++q)
        #pragma unroll
        for (int w = 0; w < 4; ++w) Sr[ty*4+q][tx*4+w] = pr[q][w];
    if (!same) {
        #pragma unroll
        for (int q = 0; q < 4; ++q)
            #pragma unroll
            for (int w = 0; w < 4; ++w) Sc[ty*4+q][tx*4+w] = pc[q][w];
    }
    __syncthreads();
    // designated writer: (bi, 0) persists final L-panel tile bi into OFF_P
    if (bj == 0) {
        float* Pp = ws + OFF_P + ((size_t)e*1792 + prow(kk) + (size_t)bi*64)*64;
        for (int idx = tid; idx < 4096; idx += 256) {
            int r = idx >> 6, c = idx & 63;
            Pp[(size_t)r*64 + c] = Sr[r][c];
        }
    }
    // SYRK
    float acc[4][4] = {};
    if (same) {
        #pragma unroll 8
        for (int p = 0; p < 64; ++p) {
            float ar[4], ac[4];
            #pragma unroll
            for (int q = 0; q < 4; ++q) { ar[q] = Sr[ty*4+q][p]; ac[q] = Sr[tx*4+q][p]; }
            #pragma unroll
            for (int q = 0; q < 4; ++q)
                #pragma unroll
                for (int w = 0; w < 4; ++w) acc[q][w] = fmaf(ar[q], ac[w], acc[q][w]);
        }
    } else {
        #pragma unroll 8
        for (int p = 0; p < 64; ++p) {
            float ar[4], ac[4];
            #pragma unroll
            for (int q = 0; q < 4; ++q) { ar[q] = Sr[ty*4+q][p]; ac[q] = Sc[tx*4+q][p]; }
            #pragma unroll
            for (int q = 0; q < 4; ++q)
                #pragma unroll
                for (int w = 0; w < 4; ++w) acc[q][w] = fmaf(ar[q], ac[w], acc[q][w]);
        }
    }
    float* Out = A + (size_t)(t0 + bi*64)*N + (t0 + bj*64);
    if (!isdiag0) {
        #pragma unroll
        for (int q = 0; q < 4; ++q)
            #pragma unroll
            for (int w = 0; w < 4; ++w)
                Out[(size_t)(ty*4+q)*N + tx*4+w] -= acc[q][w];
        return;
    }
    // ---- fused: updated (t0,t0) tile -> factor + invert -> W diag ----
    __syncthreads();
    #pragma unroll
    for (int q = 0; q < 4; ++q)
        #pragma unroll
        for (int w = 0; w < 4; ++w)
            Sr[ty*4+q][tx*4+w] = Out[(size_t)(ty*4+q)*N + tx*4+w] - acc[q][w];
    __syncthreads();

    bool act = tid < 64;
    int lane = tid;
    float a[64];
    if (act) {
        #pragma unroll
        for (int c = 0; c < 64; ++c) a[c] = Sr[c][lane];
    }
    #pragma unroll
    for (int k = 0; k < 64; ++k) {
        if (act && lane == k) {
            float dv = sqrtf(a[k]);
            a[k] = dv; colbuf[k] = dv; invdsh[k] = 1.0f/dv;
        }
        __syncthreads();
        if (act && lane > k) { a[k] *= invdsh[k]; colbuf[lane] = a[k]; }
        __syncthreads();
        if (act) {
            float lrk = a[k];
            #pragma unroll
            for (int c = k + 1; c < 64; ++c)
                a[c] = fmaf(-lrk, colbuf[c], a[c]);
        }
        __syncthreads();
    }
    if (act) {
        #pragma unroll
        for (int c = 0; c < 64; ++c) Wsh[lane][c] = a[c];   // L rows into (free) Wsh
    }
    __syncthreads();
    if (act) {
        float* W = ws + OFF_IK + (size_t)e*N*N;
        float x[64];
        int c = lane;
        #pragma unroll
        for (int r = 0; r < 64; ++r) {
            float s0 = (r == c) ? 1.0f : 0.0f, s1 = 0.f, s2 = 0.f, s3 = 0.f;
            int k = 0;
            #pragma unroll
            for (; k + 3 < r; k += 4) {
                s0 = fmaf(-Wsh[r][k],   x[k],   s0);
                s1 = fmaf(-Wsh[r][k+1], x[k+1], s1);
                s2 = fmaf(-Wsh[r][k+2], x[k+2], s2);
                s3 = fmaf(-Wsh[r][k+3], x[k+3], s3);
            }
            #pragma unroll
            for (; k < r; ++k) s0 = fmaf(-Wsh[r][k], x[k], s0);
            x[r] = ((s0 + s1) + (s2 + s3)) * invdsh[r];
        }
        #pragma unroll
        for (int r = 0; r < 64; ++r)
            W[(size_t)(t0 + r)*N + t0 + c] = x[r];
    }
}

// ---------- 3c. triangular inverse: one block per (e, column j), L panels from OFF_P ----------
__global__ __launch_bounds__(512) void k_tinvcol(float* __restrict__ ws) {
    int e = blockIdx.x / 7;
    int j = blockIdx.x % 7;
    const float* Lp = ws + OFF_P + (size_t)e*1792*64;
    float* W = ws + OFF_IK + (size_t)e*N*N;
    __shared__ float __align__(16) Sa[64][68];
    __shared__ float __align__(16) Sb[64][68];
    __shared__ float __align__(16) T [64][68];
    int tid = threadIdx.x;
    int tx = tid & 15, ty = tid >> 4;
    for (int i = j + 1; i < 8; ++i) {
        float acc[2][4] = {};
        for (int k = j; k < i; ++k) {
            __syncthreads();
            const float* Lt = Lp + ((size_t)prow(k) + (size_t)(i - k - 1)*64)*64;
            for (int idx = tid; idx < 4096; idx += 512) {
                int r = idx >> 6, c = idx & 63;
                Sa[r][c] = Lt[(size_t)r*64 + c];
                Sb[r][c] = W[(size_t)(k*64+r)*N + j*64+c];
            }
            __syncthreads();
            #pragma unroll 8
            for (int p = 0; p < 64; ++p) {
                float a0 = Sa[ty*2][p], a1 = Sa[ty*2+1][p];
                float4 bv = *(const float4*)&Sb[p][tx*4];
                acc[0][0] = fmaf(a0, bv.x, acc[0][0]); acc[0][1] = fmaf(a0, bv.y, acc[0][1]);
                acc[0][2] = fmaf(a0, bv.z, acc[0][2]); acc[0][3] = fmaf(a0, bv.w, acc[0][3]);
                acc[1][0] = fmaf(a1, bv.x, acc[1][0]); acc[1][1] = fmaf(a1, bv.y, acc[1][1]);
                acc[1][2] = fmaf(a1, bv.z, acc[1][2]); acc[1][3] = fmaf(a1, bv.w, acc[1][3]);
            }
        }
        __syncthreads();
        { float4 v0; v0.x = acc[0][0]; v0.y = acc[0][1]; v0.z = acc[0][2]; v0.w = acc[0][3];
          float4 v1; v1.x = acc[1][0]; v1.y = acc[1][1]; v1.z = acc[1][2]; v1.w = acc[1][3];
          *(float4*)&T[ty*2][tx*4] = v0;
          *(float4*)&T[ty*2+1][tx*4] = v1; }
        for (int idx = tid; idx < 4096; idx += 512) {
            int r = idx >> 6, c = idx & 63;
            Sa[r][c] = W[(size_t)(i*64+r)*N + i*64+c];    // W_ii
        }
        __syncthreads();
        float o[2][4] = {};
        #pragma unroll 8
        for (int p = 0; p < 64; ++p) {
            float a0 = Sa[ty*2][p], a1 = Sa[ty*2+1][p];
            float4 bv = *(const float4*)&T[p][tx*4];
            o[0][0] = fmaf(a0, bv.x, o[0][0]); o[0][1] = fmaf(a0, bv.y, o[0][1]);
            o[0][2] = fmaf(a0, bv.z, o[0][2]); o[0][3] = fmaf(a0, bv.w, o[0][3]);
            o[1][0] = fmaf(a1, bv.x, o[1][0]); o[1][1] = fmaf(a1, bv.y, o[1][1]);
            o[1][2] = fmaf(a1, bv.z, o[1][2]); o[1][3] = fmaf(a1, bv.w, o[1][3]);
        }
        { float4 w0; w0.x = -o[0][0]; w0.y = -o[0][1]; w0.z = -o[0][2]; w0.w = -o[0][3];
          float4 w1; w1.x = -o[1][0]; w1.y = -o[1][1]; w1.z = -o[1][2]; w1.w = -o[1][3];
          *(float4*)&W[(size_t)(i*64 + ty*2)*N + j*64 + tx*4] = w0;
          *(float4*)&W[(size_t)(i*64 + ty*2 + 1)*N + j*64 + tx*4] = w1; }
        __syncthreads();
    }
}

// ---------- 3d. iK = W^T W (into OFF_A, full symmetric) ----------
__global__ __launch_bounds__(256) void k_syrk(float* __restrict__ ws) {
    int e = blockIdx.x / 36;
    int t = blockIdx.x % 36;
    int bj = 0; while (t >= 8 - bj) { t -= 8 - bj; ++bj; }
    int bi = bj + t;
    const float* W = ws + OFF_IK + (size_t)e*N*N;
    float*      IK = ws + OFF_A  + (size_t)e*N*N;
    __shared__ float Sa[64][65], Sb[64][65];
    int tid = threadIdx.x;
    int tx = tid & 15, ty = tid >> 4;
    float acc[4][4] = {};
    for (int p = bi; p < 8; ++p) {
        __syncthreads();
        for (int idx = tid; idx < 4096; idx += 256) {
            int r = idx >> 6, cc = idx & 63;
            Sa[r][cc] = W[(size_t)(p*64+r)*N + bi*64+cc];
            Sb[r][cc] = W[(size_t)(p*64+r)*N + bj*64+cc];
        }
        __syncthreads();
        #pragma unroll 8
        for (int pr2 = 0; pr2 < 64; ++pr2) {
            float ar[4], ac[4];
            #pragma unroll
            for (int q = 0; q < 4; ++q) { ar[q] = Sa[pr2][ty*4+q]; ac[q] = Sb[pr2][tx*4+q]; }
            #pragma unroll
            for (int q = 0; q < 4; ++q)
                #pragma unroll
                for (int w = 0; w < 4; ++w) acc[q][w] = fmaf(ar[q], ac[w], acc[q][w]);
        }
    }
    #pragma unroll
    for (int q = 0; q < 4; ++q)
        #pragma unroll
        for (int w = 0; w < 4; ++w) {
            int r = bi*64 + ty*4 + q, c = bj*64 + tx*4 + w;
            IK[(size_t)r*N + c] = acc[q][w];
            IK[(size_t)c*N + r] = acc[q][w];
        }
}

// ---------- 3e. beta = iK @ Yn (4 blocks per e, m-halves combined in LDS) ----------
__global__ __launch_bounds__(256) void k_beta(float* __restrict__ ws) {
    int e = blockIdx.x >> 2, qtr = blockIdx.x & 3;
    int tid = threadIdx.x;
    int half = tid >> 7;
    int nl = tid & 127;
    int n = qtr*128 + nl;
    __shared__ float yn[N];
    __shared__ float part[2][128];
    for (int i = tid; i < N; i += 256) yn[i] = ws[OFF_YN + (size_t)e*N + i];
    __syncthreads();
    const float* IK = ws + OFF_A + (size_t)e*N*N;
    int m0 = half*256;
    float a0 = 0.f, a1 = 0.f, a2 = 0.f, a3 = 0.f;
    for (int mm = m0; mm < m0 + 256; mm += 4) {
        a0 = fmaf(IK[(size_t)mm*N + n],     yn[mm],   a0);
        a1 = fmaf(IK[(size_t)(mm+1)*N + n], yn[mm+1], a1);
        a2 = fmaf(IK[(size_t)(mm+2)*N + n], yn[mm+2], a2);
        a3 = fmaf(IK[(size_t)(mm+3)*N + n], yn[mm+3], a3);
    }
    part[half][nl] = (a0 + a1) + (a2 + a3);
    __syncthreads();
    if (tid < 128)
        ws[OFF_BETA + e*N + qtr*128 + tid] = part[0][tid] + part[1][tid];
}

// ---------- 5. per (e,n): iN, t, lb, tiL, kvec ----------
__global__ __launch_bounds__(256) void k_point(float* __restrict__ ws, const float* __restrict__ ls,
                                               const float* __restrict__ os) {
    int t = blockIdx.x*256 + threadIdx.x;
    int e = t >> 9, n = t & 511;
    float iN[D], tt[D], l[D];
    #pragma unroll
    for (int d = 0; d < D; ++d) { l[d] = ls[e*D + d]; iN[d] = ws[OFF_INP + n*D + d] / l[d]; }
    #pragma unroll
    for (int d = 0; d < D; ++d) {
        float acc = 0.f;
        #pragma unroll
        for (int j = 0; j < D; ++j) acc += ws[OFF_BINV + ((size_t)e*D + d)*D + j] * iN[j];
        tt[d] = acc;
    }
    float siNt = 0.f, siN2 = 0.f;
    #pragma unroll
    for (int d = 0; d < D; ++d) { siNt += iN[d]*tt[d]; siN2 += iN[d]*iN[d]; }
    float lbv = __expf(-0.5f * siNt) * ws[OFF_BETA + e*N + n];
    ws[OFF_LB + e*N + n] = lbv;
    #pragma unroll
    for (int d = 0; d < D; ++d) ws[OFF_TIL + ((size_t)e*N + n)*D + d] = tt[d] / l[d];
    ws[OFF_KVEC + e*N + n] = logf(os[e]) - 0.5f * siN2;
}

// ---------- 6. U/V = kvec + quadratic forms per (pair, n) ----------
__global__ __launch_bounds__(256) void k_xs(float* __restrict__ ws, const float* __restrict__ ls) {
    int t = blockIdx.x*256 + threadIdx.x;
    int pair = t / N, n = t % N;
    int a = pair / E, b = pair % E;
    int tid = threadIdx.x;
    __shared__ float Qs[16][17];
    __shared__ float i2a[16], i2b[16];
    Qs[tid >> 4][tid & 15] = ws[OFF_Q + (size_t)pair*D*D + tid];
    if (tid < 16) { float l = ls[a*D + tid]; i2a[tid] = 1.0f/(l*l); }
    else if (tid < 32) { int d = tid-16; float l = ls[b*D + d]; i2b[d] = 1.0f/(l*l); }
    __syncthreads();
    float x1[D], x2[D];
    #pragma unroll
    for (int d = 0; d < D; ++d) {
        float ip = ws[OFF_INP + n*D + d];
        x1[d] = ip * i2a[d];
        x2[d] = ip * i2b[d];
    }
    float xs1 = 0.f, xs2 = 0.f;
    #pragma unroll
    for (int j = 0; j < D; ++j) {
        float t1 = 0.f, t2 = 0.f;
        #pragma unroll
        for (int i = 0; i < D; ++i) { t1 = fmaf(x1[i], Qs[i][j], t1); t2 = fmaf(x2[i], Qs[i][j], t2); }
        xs1 = fmaf(t1, x1[j], xs1);
        xs2 = fmaf(t2, x2[j], xs2);
    }
    ws[OFF_U + (size_t)pair*N + n] = ws[OFF_KVEC + a*N + n] + xs1;
    ws[OFF_V + (size_t)pair*N + n] = ws[OFF_KVEC + b*N + n] + xs2;
}

// ---------- 7. big cross-term: d-major LDS, reg-cached A-side, b128 B-side ----------
__global__ __launch_bounds__(256) void k_S(float* __restrict__ ws, const float* __restrict__ ls) {
    int bid = blockIdx.x;
    int pair = bid >> 3, ntile = bid & 7;
    int a = pair / E, b = pair % E;
    int tid = threadIdx.x;
    int tx = tid & 15, ty = tid >> 4;
    __shared__ float Qs[16][17];
    __shared__ float i2a[16], i2b[16];
    __shared__ float __align__(16) bufAT[16][68];
    __shared__ float __align__(16) x1qT[16][68];
    __shared__ float __align__(16) bufBT[16][68];
    __shared__ float u_s[64], v_s[64], ba_s[64], bb_s[64];
    __shared__ float red[256];
    int n0 = ntile*64;
    Qs[tid >> 4][tid & 15] = ws[OFF_Q + (size_t)pair*D*D + tid];
    if (tid < 16) { float l = ls[a*D + tid]; i2a[tid] = 1.0f/(l*l); }
    else if (tid < 32) { int d = tid-16; float l = ls[b*D + d]; i2b[d] = 1.0f/(l*l); }
    __syncthreads();
    for (int idx = tid; idx < 1024; idx += 256) {
        int r = idx >> 4, d = idx & 15;
        bufAT[d][r] = ws[OFF_INP + (size_t)(n0 + r)*D + d] * i2a[d];
    }
    __syncthreads();
    for (int idx = tid; idx < 1024; idx += 256) {
        int r = idx >> 4, j = idx & 15;
        float s = 0.f;
        #pragma unroll
        for (int i = 0; i < 16; ++i) s = fmaf(bufAT[i][r], Qs[i][j], s);
        x1qT[j][r] = s;
    }
    if (tid < 64) {
        u_s[tid]  = ws[OFF_U + (size_t)pair*N + n0 + tid];
        ba_s[tid] = ws[OFF_BETA + a*N + n0 + tid];
    }
    __syncthreads();
    float4 av4[16];
    #pragma unroll
    for (int d = 0; d < 16; ++d) av4[d] = *(const float4*)&x1qT[d][ty*4];
    float uq[4], baq[4];
    #pragma unroll
    for (int q = 0; q < 4; ++q) { uq[q] = u_s[ty*4+q]; baq[q] = ba_s[ty*4+q]; }

    float sacc = 0.f, tacc = 0.f;
    for (int mt = 0; mt < 8; ++mt) {
        __syncthreads();
        for (int idx = tid; idx < 1024; idx += 256) {
            int r = idx >> 4, d = idx & 15;
            bufBT[d][r] = ws[OFF_INP + (size_t)(mt*64 + r)*D + d] * i2b[d];
        }
        if (tid < 64) {
            v_s[tid]  = ws[OFF_V + (size_t)pair*N + mt*64 + tid];
            bb_s[tid] = ws[OFF_BETA + b*N + mt*64 + tid];
        }
        __syncthreads();
        float dacc[4][4] = {};
        #pragma unroll
        for (int d = 0; d < 16; ++d) {
            float4 bv = *(const float4*)&bufBT[d][tx*4];
            float4 av = av4[d];
            dacc[0][0] = fmaf(av.x, bv.x, dacc[0][0]); dacc[0][1] = fmaf(av.x, bv.y, dacc[0][1]);
            dacc[0][2] = fmaf(av.x, bv.z, dacc[0][2]); dacc[0][3] = fmaf(av.x, bv.w, dacc[0][3]);
            dacc[1][0] = fmaf(av.y, bv.x, dacc[1][0]); dacc[1][1] = fmaf(av.y, bv.y, dacc[1][1]);
            dacc[1][2] = fmaf(av.y, bv.z, dacc[1][2]); dacc[1][3] = fmaf(av.y, bv.w, dacc[1][3]);
            dacc[2][0] = fmaf(av.z, bv.x, dacc[2][0]); dacc[2][1] = fmaf(av.z, bv.y, dacc[2][1]);
            dacc[2][2] = fmaf(av.z, bv.z, dacc[2][2]); dacc[2][3] = fmaf(av.z, bv.w, dacc[2][3]);
            dacc[3][0] = fmaf(av.w, bv.x, dacc[3][0]); dacc[3][1] = fmaf(av.w, bv.y, dacc[3][1]);
            dacc[3][2] = fmaf(av.w, bv.z, dacc[3][2]); dacc[3][3] = fmaf(av.w, bv.w, dacc[3][3]);
        }
        #pragma unroll
        for (int q = 0; q < 4; ++q) {
            #pragma unroll
            for (int w = 0; w < 4; ++w) {
                float Lv = __expf(2.f*dacc[q][w] + uq[q] + v_s[tx*4+w]);
                sacc = fmaf(baq[q] * bb_s[tx*4+w], Lv, sacc);
                if (a == b) {
                    float ik = ws[OFF_A + ((size_t)a*N + n0 + ty*4 + q)*N + mt*64 + tx*4 + w];
                    tacc = fmaf(ik, Lv, tacc);
                }
            }
        }
    }
    red[tid] = sacc; __syncthreads();
    for (int o = 128; o > 0; o >>= 1) { if (tid < o) red[tid] += red[tid+o]; __syncthreads(); }
    if (tid == 0) ws[OFF_SPART + bid] = red[0];
    if (a == b) {
        __syncthreads();
        red[tid] = tacc; __syncthreads();
        for (int o = 128; o > 0; o >>= 1) { if (tid < o) red[tid] += red[tid+o]; __syncthreads(); }
        if (tid == 0) ws[OFF_TPART + a*8 + ntile] = red[0];
    }
}

// ---------- 8. finalize ----------
__global__ __launch_bounds__(256) void k_final(float* __restrict__ ws, const float* __restrict__ s,
                                               const float* __restrict__ os, float* __restrict__ out) {
    int tid = threadIdx.x;
    __shared__ float Msh[E], Vsh[E][D], cov[D][E+1];
    __shared__ float Sm[16][17], Si[16][17];
    __shared__ float vred[16][17];

    {
        int wv = tid >> 6, lane = tid & 63;
        for (int e = wv; e < E; e += 4) {
            float sum = 0.f;
            #pragma unroll
            for (int i = 0; i < 8; ++i) sum += ws[OFF_LB + e*N + i*64 + lane];
            #pragma unroll
            for (int off = 32; off > 0; off >>= 1) sum += __shfl_xor(sum, off);
            if (lane == 0) Msh[e] = ws[OFF_C + e] * sum;
        }
    }
    for (int e = 0; e < E; ++e) {
        int d = tid & 15, sl = tid >> 4;
        float acc = 0.f;
        for (int i = 0; i < 32; ++i) {
            int n = sl*32 + i;
            acc = fmaf(ws[OFF_TIL + ((size_t)e*N + n)*D + d], ws[OFF_LB + e*N + n], acc);
        }
        vred[sl][d] = acc;
        __syncthreads();
        if (tid < 16) {
            float sum = 0.f;
            #pragma unroll
            for (int s2 = 0; s2 < 16; ++s2) sum += vred[s2][tid];
            Vsh[e][tid] = ws[OFF_C + e] * sum;
        }
        __syncthreads();
    }

    if (tid < E*E) {
        int a = tid / E, bb = tid % E;
        float acc = 0.f;
        for (int q = 0; q < 8; ++q) acc += ws[OFF_SPART + (size_t)tid*8 + q];
        if (a == bb) {
            float tr = 0.f;
            for (int q = 0; q < 8; ++q) tr += ws[OFF_TPART + a*8 + q];
            acc -= tr;
        }
        acc *= ws[OFF_ISDR + tid];
        if (a == bb) acc += os[a];
        float v = acc - Msh[a]*Msh[bb];
        v *= ws[OFF_YSTD + a] * ws[OFF_YSTD + bb];
        out[E + tid] = v;
    }
    if (tid < E) out[tid] = Msh[tid]*ws[OFF_YSTD + tid] + ws[OFF_YMEAN + tid];

    if (tid < D*E) {
        int d = tid / E, e = tid % E;
        float acc = 0.f;
        for (int k = 0; k < D; ++k) acc += ws[OFF_SSM + d*D + k] * Vsh[e][k];
        cov[d][e] = acc * ws[OFF_XSTD + d] * ws[OFF_YSTD + e];
    }
    int i = tid >> 4, j = tid & 15;
    Sm[i][j] = s[i*D + j];
    Si[i][j] = (i==j) ? 1.f : 0.f;
    __syncthreads();
    for (int k = 0; k < D; ++k) {
        float p   = Sm[k][k];
        float fik = Sm[i][k];
        float skj = Sm[k][j];
        float ikj = Si[k][j];
        __syncthreads();
        if (i == k) { Sm[k][j] = skj/p; Si[k][j] = ikj/p; }
        else        { float f = fik/p; Sm[i][j] -= f*skj; Si[i][j] -= f*ikj; }
        __syncthreads();
    }
    if (tid < D*E) {
        int d = tid / E, e = tid % E;
        float acc = 0.f;
        for (int k = 0; k < D; ++k) acc += Si[d][k] * cov[k][e];
        out[E + E*E + d*E + e] = acc;
    }
}

extern "C" void kernel_launch(void* const* d_in, const int* in_sizes, int n_in,
                              void* d_out, int out_size, void* d_ws, size_t ws_size,
                              hipStream_t stream) {
    const float* X     = (const float*)d_in[0];
    const float* Y     = (const float*)d_in[1];
    const float* m     = (const float*)d_in[2];
    const float* s     = (const float*)d_in[3];
    const float* ls    = (const float*)d_in[4];
    const float* os    = (const float*)d_in[5];
    const float* noise = (const float*)d_in[6];
    float* ws  = (float*)d_ws;
    float* out = (float*)d_out;

    k_prep   <<<1,              512, 0, stream>>>(X, Y, m, s, ws);
    k_buildA <<<E*64 + E + E*E, 256, 0, stream>>>(ws, ls, os, noise);
    k_diag64 <<<E,              64,  0, stream>>>(ws, 0);
    for (int kk = 0; kk < 7; ++kk) {
        int nb = 7 - kk;
        k_traild<<<E*nb*(nb+1)/2, 256, 0, stream>>>(ws, kk*64);
    }
    k_tinvcol <<<E*7,        512, 0, stream>>>(ws);
    k_syrk    <<<E*36,       256, 0, stream>>>(ws);
    k_beta    <<<E*4,        256, 0, stream>>>(ws);
    k_point   <<<E*N/256,    256, 0, stream>>>(ws, ls, os);
    k_xs      <<<E*E*N/256,  256, 0, stream>>>(ws, ls);
    k_S       <<<E*E*8,      256, 0, stream>>>(ws, ls);
    k_final   <<<1,          256, 0, stream>>>(ws, s, os, out);
}